// Round 1
// baseline (7316.183 us; speedup 1.0000x reference)
//
#include <hip/hip_runtime.h>
#include <math.h>

// MixingAttention forward, f32 baseline.
// Geometry: B_=2048 windows, N=64 tokens, C=256, Ca=128, NH=8, HD=16,
// B=32 images, h=w=64, windows 8x8 of 8x8 pixels.

#define BNR 0.9999950000374998f      /* 1/sqrt(1+1e-5) */
#define SQRT1_2 0.70710678118654752f

__device__ __forceinline__ float gelu_f(float x) {
  return 0.5f * x * (1.0f + erff(x * SQRT1_2));
}

// ---------------------------------------------------------------- kernel 1
// x (B_,N,256) @ attn_w (256,128) + attn_b, then LayerNorm(128) -> xattn
// block = 32 rows, 128 threads: thread (t=tid>>2, og=(tid&3)*32) owns 32 outs.
__global__ __launch_bounds__(128) void k1_attn_ln(
    const float* __restrict__ x, const float* __restrict__ aw,
    const float* __restrict__ ab, const float* __restrict__ lg,
    const float* __restrict__ lb, float* __restrict__ out) {
  __shared__ float xs[32][257];
  const int tid = threadIdx.x;
  const int r0 = blockIdx.x * 32;
  for (int idx = tid; idx < 32 * 256; idx += 128)
    xs[idx >> 8][idx & 255] = x[r0 * 256 + idx];
  __syncthreads();
  const int t = tid >> 2, og = (tid & 3) * 32;
  float acc[32];
#pragma unroll
  for (int j = 0; j < 32; ++j) acc[j] = ab[og + j];
  for (int c = 0; c < 256; ++c) {
    const float xv = xs[t][c];
    const float* wp = aw + c * 128 + og;
#pragma unroll
    for (int j = 0; j < 32; ++j) acc[j] = fmaf(xv, wp[j], acc[j]);
  }
  float ps = 0.f, pq = 0.f;
#pragma unroll
  for (int j = 0; j < 32; ++j) { ps += acc[j]; pq += acc[j] * acc[j]; }
  ps += __shfl_xor(ps, 1); ps += __shfl_xor(ps, 2);
  pq += __shfl_xor(pq, 1); pq += __shfl_xor(pq, 2);
  const float mean = ps * (1.f / 128.f);
  const float var = pq * (1.f / 128.f) - mean * mean;
  const float rstd = rsqrtf(var + 1e-5f);
  float* op = out + (r0 + t) * 128 + og;
#pragma unroll
  for (int j = 0; j < 32; ++j)
    op[j] = (acc[j] - mean) * rstd * lg[og + j] + lb[og + j];
}

// ---------------------------------------------------------------- kernel 2+5
// depthwise 3x3 conv (+conv_b, BN, GELU) on RWP(x); per-block GAP partials;
// then pr 1x1 (256->128). Block = (image b, row y, half-row xh): 32 pixels.
// Phase 1: thread = channel (256). Phase 2: thread = (o=tid&127, ph=tid>>7).
__global__ __launch_bounds__(256) void k25_conv(
    const float* __restrict__ x, const float* __restrict__ cw,
    const float* __restrict__ cb, const float* __restrict__ bg,
    const float* __restrict__ bb, const float* __restrict__ prw,
    const float* __restrict__ prb, float* __restrict__ xpr,
    float* __restrict__ gpart) {
  __shared__ float gl[32][256];
  const int tid = threadIdx.x;
  const int b = blockIdx.x >> 7;
  const int y = (blockIdx.x >> 1) & 63;
  const int xt = (blockIdx.x & 1) * 32;
  {
    const int c = tid;
    float w[9];
#pragma unroll
    for (int k = 0; k < 9; ++k) w[k] = cw[c * 9 + k];
    const float cbv = cb[c];
    const float sc = bg[c] * BNR;
    const float sb = bb[c];
    float gsum = 0.f;
    for (int p = 0; p < 32; ++p) {
      const int px = xt + p;
      float s = cbv;
#pragma unroll
      for (int dy = -1; dy <= 1; ++dy) {
        const int yy = y + dy;
        if ((unsigned)yy < 64u) {
#pragma unroll
          for (int dx = -1; dx <= 1; ++dx) {
            const int xx = px + dx;
            if ((unsigned)xx < 64u) {
              // RWP(x): image(b,y,x) -> x row (b*64 + wy*8+wx)*64 + iy*8+ix
              const int row = (b * 64 + (yy >> 3) * 8 + (xx >> 3)) * 64 +
                              (yy & 7) * 8 + (xx & 7);
              s = fmaf(w[(dy + 1) * 3 + dx + 1], x[row * 256 + c], s);
            }
          }
        }
      }
      s = s * sc + sb;
      const float g = gelu_f(s);
      gl[p][c] = g;
      gsum += g;
    }
    gpart[blockIdx.x * 256 + c] = gsum;  // deterministic GAP partial
  }
  __syncthreads();
  const int o = tid & 127, ph = tid >> 7;
  float acc[16];
#pragma unroll
  for (int j = 0; j < 16; ++j) acc[j] = 0.f;
  const float* wr = prw + o * 256;
  for (int c = 0; c < 256; ++c) {
    const float wv = wr[c];
#pragma unroll
    for (int j = 0; j < 16; ++j) acc[j] = fmaf(gl[ph * 16 + j][c], wv, acc[j]);
  }
  const float pb = prb[o];
  const int pixbase = (b * 64 + y) * 64 + xt + ph * 16;
#pragma unroll
  for (int j = 0; j < 16; ++j) xpr[(pixbase + j) * 128 + o] = acc[j] + pb;
}

// ---------------------------------------------------------------- kernel 3
// GAP reduce -> ci MLP (256->32 BN GELU ->128) -> sigmoid. One block/image.
__global__ __launch_bounds__(128) void k3_ci(
    const float* __restrict__ gp, const float* __restrict__ w1,
    const float* __restrict__ b1, const float* __restrict__ g1,
    const float* __restrict__ bb1, const float* __restrict__ w2,
    const float* __restrict__ b2, float* __restrict__ cis) {
  __shared__ float gm[256];
  __shared__ float c1[32];
  const int b = blockIdx.x, tid = threadIdx.x;
  for (int c = tid; c < 256; c += 128) {
    float s = 0.f;
    for (int p = 0; p < 128; ++p) s += gp[(b * 128 + p) * 256 + c];
    gm[c] = s * (1.f / 4096.f);
  }
  __syncthreads();
  if (tid < 32) {
    float s = b1[tid];
    for (int c = 0; c < 256; ++c) s = fmaf(gm[c], w1[tid * 256 + c], s);
    s = s * (g1[tid] * BNR) + bb1[tid];
    c1[tid] = gelu_f(s);
  }
  __syncthreads();
  float s = b2[tid];
#pragma unroll
  for (int i = 0; i < 32; ++i) s = fmaf(c1[i], w2[tid * 32 + i], s);
  cis[b * 128 + tid] = 1.f / (1.f + __expf(-s));
}

// ---------------------------------------------------------------- kernel 4
// Fused qkv GEMM + windowed attention (softmax w/ rel-pos bias) + PV.
// Block = (window, head-pair). 128 threads: (hh=tid>>6, t=tid&63).
__global__ __launch_bounds__(128) void k4_attn(
    const float* __restrict__ xa, const float* __restrict__ qw,
    const float* __restrict__ qb, const float* __restrict__ cis,
    const float* __restrict__ rpb, float* __restrict__ out) {
  __shared__ float xs[64][129];
  __shared__ float ks[2][64][17];
  __shared__ float vs[2][64][17];
  __shared__ float bs[1800];
  const int tid = threadIdx.x;
  const int win = blockIdx.x >> 2;
  const int hp = blockIdx.x & 3;
  const int hh = tid >> 6;
  const int head = hp * 2 + hh;
  const int t = tid & 63;
  for (int idx = tid; idx < 64 * 128; idx += 128)
    xs[idx >> 7][idx & 127] = xa[win * 8192 + idx];
  for (int idx = tid; idx < 1800; idx += 128) bs[idx] = rpb[idx];
  __syncthreads();
  float q[16], k[16], v[16];
  const int qoff = head * 16;
#pragma unroll
  for (int j = 0; j < 16; ++j) {
    q[j] = qb[qoff + j];
    k[j] = qb[128 + qoff + j];
    v[j] = qb[256 + qoff + j];
  }
  for (int c = 0; c < 128; ++c) {
    const float xv = xs[t][c];
    const float* wp = qw + c * 384 + qoff;
#pragma unroll
    for (int j = 0; j < 16; ++j) {
      q[j] = fmaf(xv, wp[j], q[j]);
      k[j] = fmaf(xv, wp[128 + j], k[j]);
      v[j] = fmaf(xv, wp[256 + j], v[j]);
    }
  }
  const int img = win >> 6;
#pragma unroll
  for (int j = 0; j < 16; ++j) {
    ks[hh][t][j] = k[j];
    vs[hh][t][j] = v[j] * cis[img * 128 + qoff + j];
    q[j] *= 0.25f;  // HD^-0.5
  }
  __syncthreads();
  float scr[64];
  const int iy = t >> 3, ix = t & 7;
  float mx = -1e30f;
#pragma unroll
  for (int m = 0; m < 64; ++m) {
    float s = 0.f;
#pragma unroll
    for (int j = 0; j < 16; ++j) s = fmaf(q[j], ks[hh][m][j], s);
    const int jy = m >> 3, jx = m & 7;
    s += bs[((iy - jy + 7) * 15 + (ix - jx + 7)) * 8 + head];
    scr[m] = s;
    mx = fmaxf(mx, s);
  }
  float den = 0.f;
#pragma unroll
  for (int m = 0; m < 64; ++m) { scr[m] = __expf(scr[m] - mx); den += scr[m]; }
  const float inv = 1.f / den;
  float o[16];
#pragma unroll
  for (int j = 0; j < 16; ++j) o[j] = 0.f;
#pragma unroll
  for (int m = 0; m < 64; ++m) {
    const float p = scr[m];
#pragma unroll
    for (int j = 0; j < 16; ++j) o[j] = fmaf(p, vs[hh][m][j], o[j]);
  }
  float* op = out + (win * 64 + t) * 128 + qoff;
#pragma unroll
  for (int j = 0; j < 16; ++j) op[j] = o[j] * inv;
}

// ---------------------------------------------------------------- kernel 6
// si gating MLP + sigmoid gate + BN + window-pack + LN(attn) + concat-GEMM.
// Block = 32 rows, 128 threads.
__global__ __launch_bounds__(128) void k6_tail(
    const float* __restrict__ ao, const float* __restrict__ xpr,
    const float* __restrict__ sw1, const float* __restrict__ sb1,
    const float* __restrict__ sgc, const float* __restrict__ sbc,
    const float* __restrict__ sw2, const float* __restrict__ sb2,
    const float* __restrict__ cg, const float* __restrict__ cbb,
    const float* __restrict__ ag, const float* __restrict__ abb,
    const float* __restrict__ ow, const float* __restrict__ ob,
    float* __restrict__ out) {
  __shared__ float awl[32][130];
  __shared__ float cwl[32][130];
  __shared__ float s1[32][17];
  __shared__ float sif[32];
  __shared__ float stat[32][2];
  const int tid = threadIdx.x;
  const int R0 = blockIdx.x * 32;
  for (int idx = tid; idx < 32 * 128; idx += 128) {
    const int r = idx >> 7, c = idx & 127;
    awl[r][c] = ao[(R0 + r) * 128 + c];
    const int R = R0 + r, win = R >> 6, tt = R & 63;
    const int bimg = win >> 6, wy = (win >> 3) & 7, wx = win & 7;
    const int pix = (bimg * 64 + wy * 8 + (tt >> 3)) * 64 + wx * 8 + (tt & 7);
    cwl[r][c] = xpr[pix * 128 + c];
  }
  __syncthreads();
  {
    const int r = tid >> 2, ig = (tid & 3) * 4;
    float a0 = sb1[ig], a1 = sb1[ig + 1], a2 = sb1[ig + 2], a3 = sb1[ig + 3];
    for (int c = 0; c < 128; ++c) {
      const float xv = awl[r][c];
      a0 = fmaf(xv, sw1[(ig    ) * 128 + c], a0);
      a1 = fmaf(xv, sw1[(ig + 1) * 128 + c], a1);
      a2 = fmaf(xv, sw1[(ig + 2) * 128 + c], a2);
      a3 = fmaf(xv, sw1[(ig + 3) * 128 + c], a3);
    }
    a0 = gelu_f(a0 * (sgc[ig    ] * BNR) + sbc[ig    ]);
    a1 = gelu_f(a1 * (sgc[ig + 1] * BNR) + sbc[ig + 1]);
    a2 = gelu_f(a2 * (sgc[ig + 2] * BNR) + sbc[ig + 2]);
    a3 = gelu_f(a3 * (sgc[ig + 3] * BNR) + sbc[ig + 3]);
    s1[r][ig] = a0; s1[r][ig + 1] = a1; s1[r][ig + 2] = a2; s1[r][ig + 3] = a3;
    // LN stats for attn branch (population var)
    const int qq = tid & 3;
    float ps = 0.f, pq = 0.f;
#pragma unroll
    for (int j = 0; j < 32; ++j) {
      const float v = awl[r][qq * 32 + j];
      ps += v; pq += v * v;
    }
    ps += __shfl_xor(ps, 1); ps += __shfl_xor(ps, 2);
    pq += __shfl_xor(pq, 1); pq += __shfl_xor(pq, 2);
    if (qq == 0) {
      const float mean = ps * (1.f / 128.f);
      const float var = pq * (1.f / 128.f) - mean * mean;
      stat[r][0] = mean;
      stat[r][1] = rsqrtf(var + 1e-5f);
    }
  }
  __syncthreads();
  if (tid < 32) {
    float s = sb2[0];
#pragma unroll
    for (int i = 0; i < 16; ++i) s = fmaf(s1[tid][i], sw2[i], s);
    sif[tid] = s;
  }
  __syncthreads();
  for (int idx = tid; idx < 32 * 128; idx += 128) {
    const int r = idx >> 7, c = idx & 127;
    awl[r][c] = (awl[r][c] - stat[r][0]) * stat[r][1] * ag[c] + abb[c];
    const float sg = 1.f / (1.f + __expf(-sif[r] * cwl[r][c]));
    cwl[r][c] = sg * (cg[c] * BNR) + cbb[c];
  }
  __syncthreads();
  const int t = tid >> 2, og = (tid & 3) * 64;
  float acc[64];
#pragma unroll
  for (int j = 0; j < 64; ++j) acc[j] = ob[og + j];
  for (int c = 0; c < 128; ++c) {
    const float xv = awl[t][c];
    const float* wr = ow + c * 256 + og;
#pragma unroll
    for (int j = 0; j < 64; ++j) acc[j] = fmaf(xv, wr[j], acc[j]);
  }
  for (int c = 0; c < 128; ++c) {
    const float xv = cwl[t][c];
    const float* wr = ow + (128 + c) * 256 + og;
#pragma unroll
    for (int j = 0; j < 64; ++j) acc[j] = fmaf(xv, wr[j], acc[j]);
  }
  float* op = out + (R0 + t) * 256 + og;
#pragma unroll
  for (int j = 0; j < 64; ++j) op[j] = acc[j];
}

// ---------------------------------------------------------------- launch
extern "C" void kernel_launch(void* const* d_in, const int* in_sizes, int n_in,
                              void* d_out, int out_size, void* d_ws,
                              size_t ws_size, hipStream_t stream) {
  (void)in_sizes; (void)n_in; (void)out_size; (void)ws_size;
  const float* x       = (const float*)d_in[0];
  const float* rpb     = (const float*)d_in[1];
  const float* attn_w  = (const float*)d_in[2];
  const float* attn_b  = (const float*)d_in[3];
  const float* aln_g   = (const float*)d_in[4];
  const float* aln_b   = (const float*)d_in[5];
  const float* conv_w  = (const float*)d_in[6];
  const float* conv_b  = (const float*)d_in[7];
  const float* cbn_g   = (const float*)d_in[8];
  const float* cbn_b   = (const float*)d_in[9];
  const float* ci_w1   = (const float*)d_in[10];
  const float* ci_b1   = (const float*)d_in[11];
  const float* ci_bg   = (const float*)d_in[12];
  const float* ci_bb   = (const float*)d_in[13];
  const float* ci_w2   = (const float*)d_in[14];
  const float* ci_b2   = (const float*)d_in[15];
  const float* pr_w    = (const float*)d_in[16];
  const float* pr_b    = (const float*)d_in[17];
  const float* cn_g    = (const float*)d_in[18];
  const float* cn_b    = (const float*)d_in[19];
  const float* qkv_w   = (const float*)d_in[20];
  const float* qkv_b   = (const float*)d_in[21];
  const float* si_w1   = (const float*)d_in[22];
  const float* si_b1   = (const float*)d_in[23];
  const float* si_bg   = (const float*)d_in[24];
  const float* si_bb   = (const float*)d_in[25];
  const float* si_w2   = (const float*)d_in[26];
  const float* si_b2   = (const float*)d_in[27];
  const float* an_g    = (const float*)d_in[28];
  const float* an_b    = (const float*)d_in[29];
  const float* out_w   = (const float*)d_in[30];
  const float* out_b   = (const float*)d_in[31];

  float* ws       = (float*)d_ws;
  float* xattn    = ws;                       // 16,777,216 f
  float* attn_out = ws + 16777216;            // 16,777,216 f
  float* xpr      = ws + 2 * 16777216;        // 16,777,216 f
  float* gpart    = ws + 3 * 16777216;        // 1,048,576 f (4096 blocks x 256)
  float* cis      = gpart + 1048576;          // 4096 f

  k1_attn_ln<<<4096, 128, 0, stream>>>(x, attn_w, attn_b, aln_g, aln_b, xattn);
  k25_conv<<<4096, 256, 0, stream>>>(x, conv_w, conv_b, cbn_g, cbn_b, pr_w,
                                     pr_b, xpr, gpart);
  k3_ci<<<32, 128, 0, stream>>>(gpart, ci_w1, ci_b1, ci_bg, ci_bb, ci_w2,
                                ci_b2, cis);
  k4_attn<<<8192, 128, 0, stream>>>(xattn, qkv_w, qkv_b, cis, rpb, attn_out);
  k6_tail<<<4096, 128, 0, stream>>>(attn_out, xpr, si_w1, si_b1, si_bg, si_bb,
                                    si_w2, si_b2, cn_g, cn_b, an_g, an_b,
                                    out_w, out_b, (float*)d_out);
}

// Round 2
// 1639.026 us; speedup vs baseline: 4.4637x; 4.4637x over previous
//
#include <hip/hip_runtime.h>
#include <math.h>

// MixingAttention forward, f32, LDS-staged GEMMs.
// B_=2048 windows, N=64, C=256, Ca=128, NH=8, HD=16, B=32 imgs, h=w=64.

#define BNR 0.9999950000374998f /* 1/sqrt(1+1e-5) */
#define SQRT1_2 0.70710678118654752f

__device__ __forceinline__ float gelu_f(float x) {
  return 0.5f * x * (1.0f + erff(x * SQRT1_2));
}

// ---------------------------------------------------------------- k0
// transpose pr_w (128x256, [o][c]) -> prwT (256x128, [c][o])
__global__ __launch_bounds__(256) void k0_tr(const float* __restrict__ w,
                                             float* __restrict__ wt) {
  __shared__ float t[32][33];
  const int ob = (blockIdx.x & 3) * 32;
  const int cb = (blockIdx.x >> 2) * 32;
  const int tx = threadIdx.x & 31, ty = threadIdx.x >> 5;
  for (int i = ty; i < 32; i += 8) t[i][tx] = w[(ob + i) * 256 + cb + tx];
  __syncthreads();
  for (int i = ty; i < 32; i += 8) wt[(cb + i) * 128 + ob + tx] = t[tx][i];
}

// ---------------------------------------------------------------- k1
// xattn = LN( x(131072x256) @ aw(256x128) + ab ).  Block: 64 rows, 256 thr.
// Thread (rt=tid>>5 rows rt*8+, ct=tid&31 cols ct*4+), acc[8][4]. K-tile 64.
__global__ __launch_bounds__(256) void k1_attn_ln(
    const float* __restrict__ x, const float* __restrict__ aw,
    const float* __restrict__ ab, const float* __restrict__ lg,
    const float* __restrict__ lb, float* __restrict__ out) {
  __shared__ float xsT[64][68];  // [k][row]
  __shared__ float wt[64][132];  // [k][o]
  __shared__ float gb[2][128];
  const int tid = threadIdx.x;
  const int r0 = blockIdx.x * 64;
  if (tid < 128) { gb[0][tid] = lg[tid]; gb[1][tid] = lb[tid]; }
  const int rt = tid >> 5, ct = tid & 31;
  float acc[8][4];
#pragma unroll
  for (int i = 0; i < 8; ++i)
#pragma unroll
    for (int j = 0; j < 4; ++j) acc[i][j] = 0.f;
  for (int k0 = 0; k0 < 256; k0 += 64) {
    __syncthreads();
    for (int idx = tid; idx < 64 * 64; idx += 256) {
      const int r = idx >> 6, c = idx & 63;
      xsT[c][r] = x[(r0 + r) * 256 + k0 + c];
    }
    for (int idx = tid; idx < 64 * 128; idx += 256) {
      const int kk = idx >> 7, o = idx & 127;
      wt[kk][o] = aw[(k0 + kk) * 128 + o];
    }
    __syncthreads();
#pragma unroll 4
    for (int k = 0; k < 64; ++k) {
      float xr[8];
      *(float4*)&xr[0] = *(const float4*)&xsT[k][rt * 8];
      *(float4*)&xr[4] = *(const float4*)&xsT[k][rt * 8 + 4];
      const float4 wv = *(const float4*)&wt[k][ct * 4];
      const float wr[4] = {wv.x, wv.y, wv.z, wv.w};
#pragma unroll
      for (int i = 0; i < 8; ++i)
#pragma unroll
        for (int j = 0; j < 4; ++j)
          acc[i][j] = fmaf(xr[i], wr[j], acc[i][j]);
    }
  }
  float bias[4];
#pragma unroll
  for (int j = 0; j < 4; ++j) bias[j] = ab[ct * 4 + j];
#pragma unroll
  for (int i = 0; i < 8; ++i) {
    float ps = 0.f, pq = 0.f;
#pragma unroll
    for (int j = 0; j < 4; ++j) {
      const float v = acc[i][j] + bias[j];
      acc[i][j] = v; ps += v; pq += v * v;
    }
    ps += __shfl_xor(ps, 1); ps += __shfl_xor(ps, 2);
    ps += __shfl_xor(ps, 4); ps += __shfl_xor(ps, 8); ps += __shfl_xor(ps, 16);
    pq += __shfl_xor(pq, 1); pq += __shfl_xor(pq, 2);
    pq += __shfl_xor(pq, 4); pq += __shfl_xor(pq, 8); pq += __shfl_xor(pq, 16);
    const float mean = ps * (1.f / 128.f);
    const float var = pq * (1.f / 128.f) - mean * mean;
    const float rstd = rsqrtf(var + 1e-5f);
    float4 o4;
    o4.x = (acc[i][0] - mean) * rstd * gb[0][ct * 4] + gb[1][ct * 4];
    o4.y = (acc[i][1] - mean) * rstd * gb[0][ct * 4 + 1] + gb[1][ct * 4 + 1];
    o4.z = (acc[i][2] - mean) * rstd * gb[0][ct * 4 + 2] + gb[1][ct * 4 + 2];
    o4.w = (acc[i][3] - mean) * rstd * gb[0][ct * 4 + 3] + gb[1][ct * 4 + 3];
    *(float4*)&out[(r0 + rt * 8 + i) * 128 + ct * 4] = o4;
  }
}

// ---------------------------------------------------------------- k25
// Phase 1: depthwise 3x3 + BN + GELU on RWP(x), GAP partials.
// Phase 2: pr 1x1 (256->128) from LDS, K-tiled weights (prwT [c][o]).
__global__ __launch_bounds__(256) void k25_conv(
    const float* __restrict__ x, const float* __restrict__ cw,
    const float* __restrict__ cb, const float* __restrict__ bg,
    const float* __restrict__ bb, const float* __restrict__ prwT,
    const float* __restrict__ prb, float* __restrict__ xpr,
    float* __restrict__ gpart) {
  __shared__ float gl[32][257];
  __shared__ float wt[32][132];
  const int tid = threadIdx.x;
  const int b = blockIdx.x >> 7;
  const int y = (blockIdx.x >> 1) & 63;
  const int xt = (blockIdx.x & 1) * 32;
  {
    const int c = tid;
    float w[9];
#pragma unroll
    for (int k = 0; k < 9; ++k) w[k] = cw[c * 9 + k];
    const float cbv = cb[c];
    const float sc = bg[c] * BNR;
    const float sb = bb[c];
    float gsum = 0.f;
    for (int p = 0; p < 32; ++p) {
      const int px = xt + p;
      float s = cbv;
#pragma unroll
      for (int dy = -1; dy <= 1; ++dy) {
        const int yy = y + dy;
        if ((unsigned)yy < 64u) {
#pragma unroll
          for (int dx = -1; dx <= 1; ++dx) {
            const int xx = px + dx;
            if ((unsigned)xx < 64u) {
              const int row = (b * 64 + (yy >> 3) * 8 + (xx >> 3)) * 64 +
                              (yy & 7) * 8 + (xx & 7);
              s = fmaf(w[(dy + 1) * 3 + dx + 1], x[row * 256 + c], s);
            }
          }
        }
      }
      s = s * sc + sb;
      const float g = gelu_f(s);
      gl[p][c] = g;
      gsum += g;
    }
    gpart[blockIdx.x * 256 + c] = gsum;
  }
  const int og = tid & 31, pg = tid >> 5;
  float acc[4][4];
#pragma unroll
  for (int i = 0; i < 4; ++i)
#pragma unroll
    for (int j = 0; j < 4; ++j) acc[i][j] = 0.f;
  for (int k0 = 0; k0 < 256; k0 += 32) {
    __syncthreads();
    for (int idx = tid; idx < 32 * 128; idx += 256) {
      const int kk = idx >> 7, o = idx & 127;
      wt[kk][o] = prwT[(k0 + kk) * 128 + o];
    }
    __syncthreads();
#pragma unroll 4
    for (int kk = 0; kk < 32; ++kk) {
      float xr[4];
#pragma unroll
      for (int i = 0; i < 4; ++i) xr[i] = gl[pg * 4 + i][k0 + kk];
      const float4 wv = *(const float4*)&wt[kk][og * 4];
      const float wr[4] = {wv.x, wv.y, wv.z, wv.w};
#pragma unroll
      for (int i = 0; i < 4; ++i)
#pragma unroll
        for (int j = 0; j < 4; ++j)
          acc[i][j] = fmaf(xr[i], wr[j], acc[i][j]);
    }
  }
  const float4 pbv = *(const float4*)&prb[og * 4];
#pragma unroll
  for (int i = 0; i < 4; ++i) {
    const int pix = (b * 64 + y) * 64 + xt + pg * 4 + i;
    float4 o4;
    o4.x = acc[i][0] + pbv.x; o4.y = acc[i][1] + pbv.y;
    o4.z = acc[i][2] + pbv.z; o4.w = acc[i][3] + pbv.w;
    *(float4*)&xpr[pix * 128 + og * 4] = o4;
  }
}

// ---------------------------------------------------------------- k3
__global__ __launch_bounds__(128) void k3_ci(
    const float* __restrict__ gp, const float* __restrict__ w1,
    const float* __restrict__ b1, const float* __restrict__ g1,
    const float* __restrict__ bb1, const float* __restrict__ w2,
    const float* __restrict__ b2, float* __restrict__ cis) {
  __shared__ float gm[256];
  __shared__ float c1[32];
  const int b = blockIdx.x, tid = threadIdx.x;
  for (int c = tid; c < 256; c += 128) {
    float s = 0.f;
    for (int p = 0; p < 128; ++p) s += gp[(b * 128 + p) * 256 + c];
    gm[c] = s * (1.f / 4096.f);
  }
  __syncthreads();
  if (tid < 32) {
    float s = b1[tid];
    for (int c = 0; c < 256; ++c) s = fmaf(gm[c], w1[tid * 256 + c], s);
    s = s * (g1[tid] * BNR) + bb1[tid];
    c1[tid] = gelu_f(s);
  }
  __syncthreads();
  float s = b2[tid];
#pragma unroll
  for (int i = 0; i < 32; ++i) s = fmaf(c1[i], w2[tid * 32 + i], s);
  cis[b * 128 + tid] = 1.f / (1.f + __expf(-s));
}

// ---------------------------------------------------------------- k4
// Fused qkv GEMM (64x96, K=128, outer-product tiled) + attention.
// Block = (win, hp). 128 thr. GEMM: rt=tid>>3 rows rt*4+, ct=tid&7 cols ct*12+.
__global__ __launch_bounds__(128) void k4_attn(
    const float* __restrict__ xa, const float* __restrict__ qw,
    const float* __restrict__ qb, const float* __restrict__ cis,
    const float* __restrict__ rpb, float* __restrict__ out) {
  __shared__ float xsT[32][68];   // [cc][row]
  __shared__ float wws[32][96];   // [cc][96 qkv cols of this head-pair]
  __shared__ float L[64][100];    // [row][ q0 q1 | k0 k1 | v0 v1 ] (16 each)
  __shared__ float bs2[225][2];
  __shared__ float cisl[32];
  const int tid = threadIdx.x;
  const int win = blockIdx.x >> 2, hp = blockIdx.x & 3;
  const int hh = tid >> 6, t = tid & 63;
  const int qoff = (hp * 2 + hh) * 16;
  const int img = win >> 6;
  for (int i = tid; i < 450; i += 128)
    bs2[i >> 1][i & 1] = rpb[(i >> 1) * 8 + hp * 2 + (i & 1)];
  if (tid < 32) cisl[tid] = cis[img * 128 + hp * 32 + tid];
  const int rt = tid >> 3, ct = tid & 7;
  float acc[4][12];
#pragma unroll
  for (int j = 0; j < 12; ++j) {
    const int cc = ct * 12 + j;
    const float bv = qb[(cc >> 5) * 128 + hp * 32 + (cc & 31)];
#pragma unroll
    for (int i = 0; i < 4; ++i) acc[i][j] = bv;
  }
  for (int c0 = 0; c0 < 128; c0 += 32) {
    __syncthreads();
    for (int i = tid; i < 2048; i += 128) {
      const int r = i >> 5, cc = i & 31;
      xsT[cc][r] = xa[(win * 64 + r) * 128 + c0 + cc];
    }
#pragma unroll
    for (int ch = 0; ch < 3; ++ch)
      for (int i = tid; i < 1024; i += 128) {
        const int cc = i >> 5, j = i & 31;
        wws[cc][ch * 32 + j] = qw[(c0 + cc) * 384 + ch * 128 + hp * 32 + j];
      }
    __syncthreads();
#pragma unroll 4
    for (int cc = 0; cc < 32; ++cc) {
      float xr[4];
      *(float4*)&xr[0] = *(const float4*)&xsT[cc][rt * 4];
      float wr[12];
      *(float4*)&wr[0] = *(const float4*)&wws[cc][ct * 12];
      *(float4*)&wr[4] = *(const float4*)&wws[cc][ct * 12 + 4];
      *(float4*)&wr[8] = *(const float4*)&wws[cc][ct * 12 + 8];
#pragma unroll
      for (int i = 0; i < 4; ++i)
#pragma unroll
        for (int j = 0; j < 12; ++j)
          acc[i][j] = fmaf(xr[i], wr[j], acc[i][j]);
    }
  }
  // scatter q/k/v to L (v scaled by channel-interaction sigmoid)
#pragma unroll
  for (int i = 0; i < 4; ++i)
#pragma unroll
    for (int j = 0; j < 12; ++j) {
      const int cc = ct * 12 + j;
      float a = acc[i][j];
      if (cc >= 64) a *= cisl[cc - 64];
      L[rt * 4 + i][cc] = a;
    }
  __syncthreads();
  float qr[16];
  {
    float4 a0 = *(const float4*)&L[t][qoff - hp * 32 + hh * 0 + hh * 16 - hh * 16 + hh * 16];
    // (simplify: q cols are hh*16 .. hh*16+15)
  }
#pragma unroll
  for (int j = 0; j < 16; ++j) qr[j] = L[t][hh * 16 + j] * 0.25f;
  const int iy = t >> 3, ix = t & 7;
  float scr[64];
  float mx = -1e30f;
#pragma unroll
  for (int m = 0; m < 64; ++m) {
    float kr[16];
    *(float4*)&kr[0]  = *(const float4*)&L[m][32 + hh * 16];
    *(float4*)&kr[4]  = *(const float4*)&L[m][32 + hh * 16 + 4];
    *(float4*)&kr[8]  = *(const float4*)&L[m][32 + hh * 16 + 8];
    *(float4*)&kr[12] = *(const float4*)&L[m][32 + hh * 16 + 12];
    float s = 0.f;
#pragma unroll
    for (int j = 0; j < 16; ++j) s = fmaf(qr[j], kr[j], s);
    const int jy = m >> 3, jx = m & 7;
    s += bs2[(iy - jy + 7) * 15 + (ix - jx + 7)][hh];
    scr[m] = s;
    mx = fmaxf(mx, s);
  }
  float den = 0.f;
#pragma unroll
  for (int m = 0; m < 64; ++m) { scr[m] = __expf(scr[m] - mx); den += scr[m]; }
  const float inv = 1.f / den;
  float o[16];
#pragma unroll
  for (int j = 0; j < 16; ++j) o[j] = 0.f;
#pragma unroll
  for (int m = 0; m < 64; ++m) {
    const float p = scr[m];
    float vr[16];
    *(float4*)&vr[0]  = *(const float4*)&L[m][64 + hh * 16];
    *(float4*)&vr[4]  = *(const float4*)&L[m][64 + hh * 16 + 4];
    *(float4*)&vr[8]  = *(const float4*)&L[m][64 + hh * 16 + 8];
    *(float4*)&vr[12] = *(const float4*)&L[m][64 + hh * 16 + 12];
#pragma unroll
    for (int j = 0; j < 16; ++j) o[j] = fmaf(p, vr[j], o[j]);
  }
  float* op = out + (win * 64 + t) * 128 + qoff;
#pragma unroll
  for (int j = 0; j < 16; j += 4) {
    float4 o4; o4.x = o[j] * inv; o4.y = o[j + 1] * inv;
    o4.z = o[j + 2] * inv; o4.w = o[j + 3] * inv;
    *(float4*)&op[j] = o4;
  }
}

// ---------------------------------------------------------------- k6
// si MLP + sigmoid gate + BN + window-pack + LN + concat GEMM (K-tiled LDS).
__global__ __launch_bounds__(128) void k6_tail(
    const float* __restrict__ ao, const float* __restrict__ xpr,
    const float* __restrict__ sw1, const float* __restrict__ sb1,
    const float* __restrict__ sgc, const float* __restrict__ sbc,
    const float* __restrict__ sw2, const float* __restrict__ sb2,
    const float* __restrict__ cg, const float* __restrict__ cbb,
    const float* __restrict__ ag, const float* __restrict__ abb,
    const float* __restrict__ ow, const float* __restrict__ ob,
    float* __restrict__ out) {
  __shared__ float awl[32][130];
  __shared__ float cwl[32][130];
  __shared__ float wt[16][256];  // reused: first 2064 floats = sws[16][129]
  __shared__ float s1[32][17];
  __shared__ float sif[32];
  __shared__ float stat[32][2];
  float* sws = &wt[0][0];
  const int tid = threadIdx.x;
  const int R0 = blockIdx.x * 32;
  for (int idx = tid; idx < 32 * 128; idx += 128) {
    const int r = idx >> 7, c = idx & 127;
    awl[r][c] = ao[(R0 + r) * 128 + c];
    const int R = R0 + r, win = R >> 6, tt = R & 63;
    const int bimg = win >> 6, wy = (win >> 3) & 7, wx = win & 7;
    const int pix = (bimg * 64 + wy * 8 + (tt >> 3)) * 64 + wx * 8 + (tt & 7);
    cwl[r][c] = xpr[pix * 128 + c];
  }
  for (int idx = tid; idx < 16 * 128; idx += 128) {
    const int o = idx >> 7, c = idx & 127;
    sws[o * 129 + c] = sw1[o * 128 + c];
  }
  __syncthreads();
  {
    const int r = tid >> 2, ig = (tid & 3) * 4;
    float a0 = sb1[ig], a1 = sb1[ig + 1], a2 = sb1[ig + 2], a3 = sb1[ig + 3];
    for (int c = 0; c < 128; ++c) {
      const float xv = awl[r][c];
      a0 = fmaf(xv, sws[(ig    ) * 129 + c], a0);
      a1 = fmaf(xv, sws[(ig + 1) * 129 + c], a1);
      a2 = fmaf(xv, sws[(ig + 2) * 129 + c], a2);
      a3 = fmaf(xv, sws[(ig + 3) * 129 + c], a3);
    }
    a0 = gelu_f(a0 * (sgc[ig    ] * BNR) + sbc[ig    ]);
    a1 = gelu_f(a1 * (sgc[ig + 1] * BNR) + sbc[ig + 1]);
    a2 = gelu_f(a2 * (sgc[ig + 2] * BNR) + sbc[ig + 2]);
    a3 = gelu_f(a3 * (sgc[ig + 3] * BNR) + sbc[ig + 3]);
    s1[r][ig] = a0; s1[r][ig + 1] = a1; s1[r][ig + 2] = a2; s1[r][ig + 3] = a3;
    const int qq = tid & 3;
    float ps = 0.f, pq = 0.f;
#pragma unroll
    for (int j = 0; j < 32; ++j) {
      const float v = awl[r][qq * 32 + j];
      ps += v; pq += v * v;
    }
    ps += __shfl_xor(ps, 1); ps += __shfl_xor(ps, 2);
    pq += __shfl_xor(pq, 1); pq += __shfl_xor(pq, 2);
    if (qq == 0) {
      const float mean = ps * (1.f / 128.f);
      const float var = pq * (1.f / 128.f) - mean * mean;
      stat[r][0] = mean;
      stat[r][1] = rsqrtf(var + 1e-5f);
    }
  }
  __syncthreads();
  if (tid < 32) {
    float s = sb2[0];
#pragma unroll
    for (int i = 0; i < 16; ++i) s = fmaf(s1[tid][i], sw2[i], s);
    sif[tid] = s;
  }
  __syncthreads();
  for (int idx = tid; idx < 32 * 128; idx += 128) {
    const int r = idx >> 7, c = idx & 127;
    awl[r][c] = (awl[r][c] - stat[r][0]) * stat[r][1] * ag[c] + abb[c];
    const float sg = 1.f / (1.f + __expf(-sif[r] * cwl[r][c]));
    cwl[r][c] = sg * (cg[c] * BNR) + cbb[c];
  }
  // final GEMM: 32 rows x 256 cols, K=256 in 16-wide tiles.
  const int rt = tid >> 5, ot = tid & 31;
  float acc[8][8];
#pragma unroll
  for (int j = 0; j < 8; ++j) {
    const float bv = ob[ot * 8 + j];
#pragma unroll
    for (int i = 0; i < 8; ++i) acc[i][j] = bv;
  }
  for (int k0 = 0; k0 < 256; k0 += 16) {
    __syncthreads();
    for (int i = tid; i < 16 * 256; i += 128) {
      const int kk = i >> 8, o = i & 255;
      wt[kk][o] = ow[(k0 + kk) * 256 + o];
    }
    __syncthreads();
    const float(*xsrc)[130] = (k0 < 128) ? awl : cwl;
    const int kb = (k0 < 128) ? k0 : k0 - 128;
#pragma unroll 4
    for (int kk = 0; kk < 16; ++kk) {
      float xr[8];
#pragma unroll
      for (int i = 0; i < 8; ++i) xr[i] = xsrc[rt * 8 + i][kb + kk];
      float wr[8];
      *(float4*)&wr[0] = *(const float4*)&wt[kk][ot * 8];
      *(float4*)&wr[4] = *(const float4*)&wt[kk][ot * 8 + 4];
#pragma unroll
      for (int i = 0; i < 8; ++i)
#pragma unroll
        for (int j = 0; j < 8; ++j)
          acc[i][j] = fmaf(xr[i], wr[j], acc[i][j]);
    }
  }
#pragma unroll
  for (int i = 0; i < 8; ++i) {
    float4 a0, a1;
    a0.x = acc[i][0]; a0.y = acc[i][1]; a0.z = acc[i][2]; a0.w = acc[i][3];
    a1.x = acc[i][4]; a1.y = acc[i][5]; a1.z = acc[i][6]; a1.w = acc[i][7];
    float* op = &out[(R0 + rt * 8 + i) * 256 + ot * 8];
    *(float4*)op = a0;
    *(float4*)(op + 4) = a1;
  }
}

// ---------------------------------------------------------------- launch
extern "C" void kernel_launch(void* const* d_in, const int* in_sizes, int n_in,
                              void* d_out, int out_size, void* d_ws,
                              size_t ws_size, hipStream_t stream) {
  (void)in_sizes; (void)n_in; (void)out_size; (void)ws_size;
  const float* x      = (const float*)d_in[0];
  const float* rpb    = (const float*)d_in[1];
  const float* attn_w = (const float*)d_in[2];
  const float* attn_b = (const float*)d_in[3];
  const float* aln_g  = (const float*)d_in[4];
  const float* aln_b  = (const float*)d_in[5];
  const float* conv_w = (const float*)d_in[6];
  const float* conv_b = (const float*)d_in[7];
  const float* cbn_g  = (const float*)d_in[8];
  const float* cbn_b  = (const float*)d_in[9];
  const float* ci_w1  = (const float*)d_in[10];
  const float* ci_b1  = (const float*)d_in[11];
  const float* ci_bg  = (const float*)d_in[12];
  const float* ci_bb  = (const float*)d_in[13];
  const float* ci_w2  = (const float*)d_in[14];
  const float* ci_b2  = (const float*)d_in[15];
  const float* pr_w   = (const float*)d_in[16];
  const float* pr_b   = (const float*)d_in[17];
  const float* cn_g   = (const float*)d_in[18];
  const float* cn_b   = (const float*)d_in[19];
  const float* qkv_w  = (const float*)d_in[20];
  const float* qkv_b  = (const float*)d_in[21];
  const float* si_w1  = (const float*)d_in[22];
  const float* si_b1  = (const float*)d_in[23];
  const float* si_bg  = (const float*)d_in[24];
  const float* si_bb  = (const float*)d_in[25];
  const float* si_w2  = (const float*)d_in[26];
  const float* si_b2  = (const float*)d_in[27];
  const float* an_g   = (const float*)d_in[28];
  const float* an_b   = (const float*)d_in[29];
  const float* out_w  = (const float*)d_in[30];
  const float* out_b  = (const float*)d_in[31];

  float* ws       = (float*)d_ws;
  float* xattn    = ws;                 // 16,777,216 f
  float* attn_out = ws + 16777216;      // 16,777,216 f
  float* xpr      = ws + 2 * 16777216;  // 16,777,216 f
  float* gpart    = ws + 3 * 16777216;  // 1,048,576 f
  float* cis      = gpart + 1048576;    // 4,096 f
  float* prwT     = cis + 4096;         // 32,768 f

  k0_tr<<<32, 256, 0, stream>>>(pr_w, prwT);
  k1_attn_ln<<<2048, 256, 0, stream>>>(x, attn_w, attn_b, aln_g, aln_b, xattn);
  k25_conv<<<4096, 256, 0, stream>>>(x, conv_w, conv_b, cbn_g, cbn_b, prwT,
                                     pr_b, xpr, gpart);
  k3_ci<<<32, 128, 0, stream>>>(gpart, ci_w1, ci_b1, ci_bg, ci_bb, ci_w2,
                                ci_b2, cis);
  k4_attn<<<8192, 128, 0, stream>>>(xattn, qkv_w, qkv_b, cis, rpb, attn_out);
  k6_tail<<<4096, 128, 0, stream>>>(attn_out, xpr, si_w1, si_b1, si_bg, si_bb,
                                    si_w2, si_b2, cn_g, cn_b, an_g, an_b,
                                    out_w, out_b, (float*)d_out);
}

// Round 3
// 851.092 us; speedup vs baseline: 8.5962x; 1.9258x over previous
//
#include <hip/hip_runtime.h>
#include <math.h>

// MixingAttention forward: bf16 MFMA GEMMs + f32 epilogues.
// B_=2048 windows, N=64, C=256, Ca=128, NH=8, HD=16, B=32 imgs, h=w=64.

#define BNR 0.9999950000374998f /* 1/sqrt(1+1e-5) */
#define SQRT1_2 0.70710678118654752f

typedef __attribute__((ext_vector_type(8))) short short8;
typedef __attribute__((ext_vector_type(4))) float f32x4;

__device__ __forceinline__ float gelu_f(float x) {
  return 0.5f * x * (1.0f + erff(x * SQRT1_2));
}
__device__ __forceinline__ unsigned short f2bf(float f) {
  unsigned int u = __builtin_bit_cast(unsigned int, f);
  u += 0x7fffu + ((u >> 16) & 1u);
  return (unsigned short)(u >> 16);
}
__device__ __forceinline__ float bf2f(unsigned short h) {
  unsigned int u = ((unsigned int)h) << 16;
  return __builtin_bit_cast(float, u);
}
__device__ __forceinline__ void ld8(const unsigned short* p, float* o) {
  const short8 v = *(const short8*)p;
#pragma unroll
  for (int i = 0; i < 8; ++i) o[i] = bf2f((unsigned short)v[i]);
}

// ---------------------------------------------------------------- kx
// x f32 -> bf16
__global__ __launch_bounds__(256) void kx_cvt(const float4* __restrict__ x,
                                              ushort4* __restrict__ xb) {
  const int n4 = 131072 * 64;
  for (int i = blockIdx.x * 256 + threadIdx.x; i < n4; i += 2048 * 256) {
    const float4 v = x[i];
    ushort4 o;
    o.x = f2bf(v.x); o.y = f2bf(v.y); o.z = f2bf(v.z); o.w = f2bf(v.w);
    xb[i] = o;
  }
}

// ---------------------------------------------------------------- kpack
// Pack W[k][n] (or W[n][k] if trans) into MFMA B-frag order:
// dst[(fs*64+l)*8+i] = W[ks*32+(l>>4)*8+i][nt*16+(l&15)], fs=ks*NT+nt.
__global__ __launch_bounds__(256) void kpack(
    const float* __restrict__ aw, const float* __restrict__ qw,
    const float* __restrict__ prw, const float* __restrict__ ow,
    unsigned short* __restrict__ awp, unsigned short* __restrict__ qwp,
    unsigned short* __restrict__ prwp, unsigned short* __restrict__ owp) {
  const int b = blockIdx.x;
  const float* src; unsigned short* dst; int fs, K, N, NT, trans;
  if (b < 64)       { fs = b;       src = aw;  dst = awp;  K = 256; N = 128; NT = 8;  trans = 0; }
  else if (b < 160) { fs = b - 64;  src = qw;  dst = qwp;  K = 128; N = 384; NT = 24; trans = 0; }
  else if (b < 224) { fs = b - 160; src = prw; dst = prwp; K = 256; N = 128; NT = 8;  trans = 1; }
  else              { fs = b - 224; src = ow;  dst = owp;  K = 256; N = 256; NT = 16; trans = 0; }
  const int ks = fs / NT, nt = fs % NT;
  for (int idx = threadIdx.x; idx < 512; idx += 256) {
    const int l = idx >> 3, i = idx & 7;
    const int k = ks * 32 + ((l >> 4) << 3) + i, n = nt * 16 + (l & 15);
    const float v = trans ? src[n * K + k] : src[k * N + n];
    dst[(fs * 64 + l) * 8 + i] = f2bf(v);
  }
}

// ---------------------------------------------------------------- k1
// xattn = bf16( LN( xb @ attn_w + ab ) ). 64 rows/block, 4 waves, no LDS.
__global__ __launch_bounds__(256) void k1_attn_ln(
    const unsigned short* __restrict__ xb, const unsigned short* __restrict__ awp,
    const float* __restrict__ ab, const float* __restrict__ lg,
    const float* __restrict__ lb, unsigned short* __restrict__ xattn) {
  const int tid = threadIdx.x, w = tid >> 6, l = tid & 63;
  const int lr = l & 15, lg4 = l >> 4;
  const int r0 = blockIdx.x * 64 + w * 16;
  short8 a[8];
  const unsigned short* ap = xb + (size_t)(r0 + lr) * 256 + lg4 * 8;
#pragma unroll
  for (int ks = 0; ks < 8; ++ks) a[ks] = *(const short8*)(ap + ks * 32);
  f32x4 acc[8];
#pragma unroll
  for (int nt = 0; nt < 8; ++nt) acc[nt] = (f32x4)0.f;
#pragma unroll
  for (int nt = 0; nt < 8; ++nt)
#pragma unroll
    for (int ks = 0; ks < 8; ++ks) {
      const short8 bfr = *(const short8*)(awp + ((ks * 8 + nt) * 64 + l) * 8);
      acc[nt] = __builtin_amdgcn_mfma_f32_16x16x32_bf16(a[ks], bfr, acc[nt], 0, 0, 0);
    }
  float bias[8], gam[8], bet[8];
#pragma unroll
  for (int nt = 0; nt < 8; ++nt) {
    const int col = nt * 16 + lr;
    bias[nt] = ab[col]; gam[nt] = lg[col]; bet[nt] = lb[col];
  }
#pragma unroll
  for (int j = 0; j < 4; ++j) {
    float s = 0.f, qq = 0.f;
#pragma unroll
    for (int nt = 0; nt < 8; ++nt) {
      const float v = acc[nt][j] + bias[nt];
      acc[nt][j] = v; s += v; qq += v * v;
    }
    s += __shfl_xor(s, 1); s += __shfl_xor(s, 2);
    s += __shfl_xor(s, 4); s += __shfl_xor(s, 8);
    qq += __shfl_xor(qq, 1); qq += __shfl_xor(qq, 2);
    qq += __shfl_xor(qq, 4); qq += __shfl_xor(qq, 8);
    const float mean = s * (1.f / 128.f);
    const float var = qq * (1.f / 128.f) - mean * mean;
    const float rstd = rsqrtf(var + 1e-5f);
    const int row = r0 + lg4 * 4 + j;
#pragma unroll
    for (int nt = 0; nt < 8; ++nt)
      xattn[(size_t)row * 128 + nt * 16 + lr] =
          f2bf((acc[nt][j] - mean) * rstd * gam[nt] + bet[nt]);
  }
}

// ---------------------------------------------------------------- k25
// Phase1: depthwise 3x3 + BN + GELU (f32) -> gl bf16 LDS + GAP partials.
// Phase2: pr 1x1 via MFMA (K=256 -> N=128), xpr bf16.
__global__ __launch_bounds__(256) void k25_conv(
    const float* __restrict__ x, const float* __restrict__ cw,
    const float* __restrict__ cb, const float* __restrict__ bg,
    const float* __restrict__ bb, const unsigned short* __restrict__ prwp,
    const float* __restrict__ prb, unsigned short* __restrict__ xpr,
    float* __restrict__ gpart) {
  __shared__ unsigned short gl[32][264];
  const int tid = threadIdx.x;
  const int b = blockIdx.x >> 7;
  const int y = (blockIdx.x >> 1) & 63;
  const int xt = (blockIdx.x & 1) * 32;
  {
    const int c = tid;
    float w9[9];
#pragma unroll
    for (int k = 0; k < 9; ++k) w9[k] = cw[c * 9 + k];
    const float cbv = cb[c];
    const float sc = bg[c] * BNR;
    const float sb = bb[c];
    float gsum = 0.f;
    for (int p = 0; p < 32; ++p) {
      const int px = xt + p;
      float s = cbv;
#pragma unroll
      for (int dy = -1; dy <= 1; ++dy) {
        const int yy = y + dy;
        if ((unsigned)yy < 64u) {
#pragma unroll
          for (int dx = -1; dx <= 1; ++dx) {
            const int xx = px + dx;
            if ((unsigned)xx < 64u) {
              const int row = (b * 64 + (yy >> 3) * 8 + (xx >> 3)) * 64 +
                              (yy & 7) * 8 + (xx & 7);
              s = fmaf(w9[(dy + 1) * 3 + dx + 1], x[(size_t)row * 256 + c], s);
            }
          }
        }
      }
      s = s * sc + sb;
      const float g = gelu_f(s);
      gl[p][c] = f2bf(g);
      gsum += g;
    }
    gpart[(size_t)blockIdx.x * 256 + c] = gsum;
  }
  __syncthreads();
  const int w = tid >> 6, l = tid & 63, lr = l & 15, lg4 = l >> 4;
  const int mr0 = (w & 1) * 16, nt0 = (w >> 1) * 4;
  short8 a[8];
#pragma unroll
  for (int ks = 0; ks < 8; ++ks)
    a[ks] = *(const short8*)&gl[mr0 + lr][ks * 32 + lg4 * 8];
  f32x4 acc[4];
#pragma unroll
  for (int nt = 0; nt < 4; ++nt) acc[nt] = (f32x4)0.f;
#pragma unroll
  for (int nt = 0; nt < 4; ++nt)
#pragma unroll
    for (int ks = 0; ks < 8; ++ks) {
      const short8 bfr =
          *(const short8*)(prwp + ((ks * 8 + nt0 + nt) * 64 + l) * 8);
      acc[nt] = __builtin_amdgcn_mfma_f32_16x16x32_bf16(a[ks], bfr, acc[nt], 0, 0, 0);
    }
#pragma unroll
  for (int nt = 0; nt < 4; ++nt) {
    const int col = (nt0 + nt) * 16 + lr;
    const float bv = prb[col];
#pragma unroll
    for (int j = 0; j < 4; ++j) {
      const int pix = (b * 64 + y) * 64 + xt + mr0 + lg4 * 4 + j;
      xpr[(size_t)pix * 128 + col] = f2bf(acc[nt][j] + bv);
    }
  }
}

// ---------------------------------------------------------------- k3
__global__ __launch_bounds__(128) void k3_ci(
    const float* __restrict__ gp, const float* __restrict__ w1,
    const float* __restrict__ b1, const float* __restrict__ g1,
    const float* __restrict__ bb1, const float* __restrict__ w2,
    const float* __restrict__ b2, float* __restrict__ cis) {
  __shared__ float gm[256];
  __shared__ float c1[32];
  const int b = blockIdx.x, tid = threadIdx.x;
  for (int c = tid; c < 256; c += 128) {
    float s = 0.f;
    for (int p = 0; p < 128; ++p) s += gp[(size_t)(b * 128 + p) * 256 + c];
    gm[c] = s * (1.f / 4096.f);
  }
  __syncthreads();
  if (tid < 32) {
    float s = b1[tid];
    for (int c = 0; c < 256; ++c) s = fmaf(gm[c], w1[tid * 256 + c], s);
    s = s * (g1[tid] * BNR) + bb1[tid];
    c1[tid] = gelu_f(s);
  }
  __syncthreads();
  float s = b2[tid];
#pragma unroll
  for (int i = 0; i < 32; ++i) s = fmaf(c1[i], w2[tid * 32 + i], s);
  cis[b * 128 + tid] = 1.f / (1.f + __expf(-s));
}

// ---------------------------------------------------------------- k4
// qkv GEMM via MFMA (M=64,N=384,K=128) -> LDS bf16; f32 attention.
__global__ __launch_bounds__(256) void k4_attn(
    const unsigned short* __restrict__ xa, const unsigned short* __restrict__ qwp,
    const float* __restrict__ qb, const float* __restrict__ cis,
    const float* __restrict__ rpb, unsigned short* __restrict__ attn) {
  __shared__ unsigned short qkvs[64][392];
  __shared__ float bsl[1800];   // [head][225]
  __shared__ float cisl[128];
  __shared__ float qbl[384];
  const int tid = threadIdx.x;
  const int win = blockIdx.x, img = win >> 6;
  for (int i = tid; i < 1800; i += 256) {
    const int hh = i / 225, d = i % 225;
    bsl[hh * 225 + d] = rpb[d * 8 + hh];
  }
  for (int i = tid; i < 128; i += 256) cisl[i] = cis[img * 128 + i];
  for (int i = tid; i < 384; i += 256) qbl[i] = qb[i];
  const int w = tid >> 6, l = tid & 63, lr = l & 15, lg4 = l >> 4;
  // qkv GEMM
  short8 a[4];
  const unsigned short* ap = xa + (size_t)(win * 64 + w * 16 + lr) * 128 + lg4 * 8;
#pragma unroll
  for (int ks = 0; ks < 4; ++ks) a[ks] = *(const short8*)(ap + ks * 32);
  f32x4 acc[24];
#pragma unroll
  for (int nt = 0; nt < 24; ++nt) acc[nt] = (f32x4)0.f;
#pragma unroll
  for (int nt = 0; nt < 24; ++nt)
#pragma unroll
    for (int ks = 0; ks < 4; ++ks) {
      const short8 bfr = *(const short8*)(qwp + ((ks * 24 + nt) * 64 + l) * 8);
      acc[nt] = __builtin_amdgcn_mfma_f32_16x16x32_bf16(a[ks], bfr, acc[nt], 0, 0, 0);
    }
  __syncthreads();  // staging done (covers bsl/cisl/qbl)
#pragma unroll
  for (int nt = 0; nt < 24; ++nt) {
    const int col = nt * 16 + lr;
#pragma unroll
    for (int j = 0; j < 4; ++j) {
      float v = acc[nt][j] + qbl[col];
      if (col < 128) v *= 0.25f;            // q * HD^-0.5
      else if (col >= 256) v *= cisl[col - 256];  // v * sigmoid(ci)
      qkvs[w * 16 + lg4 * 4 + j][col] = f2bf(v);
    }
  }
  __syncthreads();
  // attention: thread = (row t, head hq), 2 head-iterations
  const int t = tid & 63, hq = tid >> 6;
  const int iy = t >> 3, ix = t & 7;
  for (int hi = 0; hi < 2; ++hi) {
    const int hh = hq + hi * 4;
    float qv[16];
    ld8(&qkvs[t][hh * 16], qv);
    ld8(&qkvs[t][hh * 16 + 8], qv + 8);
    float scr[64];
    float mx = -1e30f;
#pragma unroll
    for (int m = 0; m < 64; ++m) {
      float kf[16];
      ld8(&qkvs[m][128 + hh * 16], kf);
      ld8(&qkvs[m][128 + hh * 16 + 8], kf + 8);
      float s = 0.f;
#pragma unroll
      for (int j = 0; j < 16; ++j) s = fmaf(qv[j], kf[j], s);
      const int jy = m >> 3, jx = m & 7;
      s += bsl[hh * 225 + (iy - jy + 7) * 15 + (ix - jx + 7)];
      scr[m] = s;
      mx = fmaxf(mx, s);
    }
    float den = 0.f;
#pragma unroll
    for (int m = 0; m < 64; ++m) { scr[m] = __expf(scr[m] - mx); den += scr[m]; }
    const float inv = 1.f / den;
    float o[16];
#pragma unroll
    for (int j = 0; j < 16; ++j) o[j] = 0.f;
#pragma unroll
    for (int m = 0; m < 64; ++m) {
      float vf[16];
      ld8(&qkvs[m][256 + hh * 16], vf);
      ld8(&qkvs[m][256 + hh * 16 + 8], vf + 8);
      const float p = scr[m];
#pragma unroll
      for (int j = 0; j < 16; ++j) o[j] = fmaf(p, vf[j], o[j]);
    }
    unsigned int pk[8];
#pragma unroll
    for (int j = 0; j < 8; ++j)
      pk[j] = (unsigned int)f2bf(o[2 * j] * inv) |
              ((unsigned int)f2bf(o[2 * j + 1] * inv) << 16);
    uint4* dst = (uint4*)&attn[(size_t)(win * 64 + t) * 128 + hh * 16];
    dst[0] = make_uint4(pk[0], pk[1], pk[2], pk[3]);
    dst[1] = make_uint4(pk[4], pk[5], pk[6], pk[7]);
  }
}

// ---------------------------------------------------------------- k6
// Stage [attn | xpr] bf16 tile; LN stats + si MLP + gating f32;
// final 256x256 GEMM via MFMA.
__global__ __launch_bounds__(256) void k6_tail(
    const unsigned short* __restrict__ attn, const unsigned short* __restrict__ xpr,
    const float* __restrict__ sw1, const float* __restrict__ sb1,
    const float* __restrict__ sgc, const float* __restrict__ sbc,
    const float* __restrict__ sw2, const float* __restrict__ sb2,
    const float* __restrict__ cg, const float* __restrict__ cbb,
    const float* __restrict__ ag, const float* __restrict__ abb,
    const unsigned short* __restrict__ owp, const float* __restrict__ ob,
    float* __restrict__ out) {
  __shared__ unsigned short At[64][264];
  __shared__ float s1l[64][17];
  __shared__ float sifl[64];
  __shared__ float statl[64][2];
  const int tid = threadIdx.x;
  const int R0 = blockIdx.x * 64;
  for (int i = tid; i < 1024; i += 256) {
    const int r = i >> 4, cb = (i & 15) * 8;
    *(uint4*)&At[r][cb] = *(const uint4*)&attn[(size_t)(R0 + r) * 128 + cb];
    const int R = R0 + r, win = R >> 6, tt = R & 63;
    const int bimg = win >> 6, wy = (win >> 3) & 7, wx = win & 7;
    const int pix = (bimg * 64 + wy * 8 + (tt >> 3)) * 64 + wx * 8 + (tt & 7);
    *(uint4*)&At[r][128 + cb] = *(const uint4*)&xpr[(size_t)pix * 128 + cb];
  }
  __syncthreads();
  {
    const int r = tid >> 2, q = tid & 3;
    float xv[32];
#pragma unroll
    for (int b8 = 0; b8 < 4; ++b8) ld8(&At[r][q * 32 + b8 * 8], xv + b8 * 8);
    float ps = 0.f, pq = 0.f;
#pragma unroll
    for (int j = 0; j < 32; ++j) { ps += xv[j]; pq += xv[j] * xv[j]; }
    ps += __shfl_xor(ps, 1); ps += __shfl_xor(ps, 2);
    pq += __shfl_xor(pq, 1); pq += __shfl_xor(pq, 2);
    if (q == 0) {
      const float mean = ps * (1.f / 128.f);
      const float var = pq * (1.f / 128.f) - mean * mean;
      statl[r][0] = mean;
      statl[r][1] = rsqrtf(var + 1e-5f);
    }
    float part[16];
#pragma unroll
    for (int o = 0; o < 16; ++o) {
      float s = 0.f;
      const float* wr = sw1 + o * 128 + q * 32;
#pragma unroll
      for (int j = 0; j < 32; ++j) s = fmaf(xv[j], wr[j], s);
      part[o] = s;
    }
#pragma unroll
    for (int o = 0; o < 16; ++o) {
      part[o] += __shfl_xor(part[o], 1);
      part[o] += __shfl_xor(part[o], 2);
    }
#pragma unroll
    for (int jo = 0; jo < 4; ++jo) {
      const int o = q * 4 + jo;
      float s = part[o] + sb1[o];
      s = s * (sgc[o] * BNR) + sbc[o];
      s1l[r][o] = gelu_f(s);
    }
  }
  __syncthreads();
  if (tid < 64) {
    float s = sb2[0];
#pragma unroll
    for (int i = 0; i < 16; ++i) s = fmaf(s1l[tid][i], sw2[i], s);
    sifl[tid] = s;
  }
  __syncthreads();
  for (int i = tid; i < 8192; i += 256) {
    const int r = i >> 7, c = i & 127;
    float a = bf2f(At[r][c]);
    a = (a - statl[r][0]) * statl[r][1] * ag[c] + abb[c];
    At[r][c] = f2bf(a);
    const float cv = bf2f(At[r][128 + c]);
    const float g = 1.f / (1.f + __expf(-sifl[r] * cv));
    At[r][128 + c] = f2bf(g * (cg[c] * BNR) + cbb[c]);
  }
  __syncthreads();
  const int w = tid >> 6, l = tid & 63, lr = l & 15, lg4 = l >> 4;
  short8 a[8];
#pragma unroll
  for (int ks = 0; ks < 8; ++ks)
    a[ks] = *(const short8*)&At[w * 16 + lr][ks * 32 + lg4 * 8];
  f32x4 acc[16];
#pragma unroll
  for (int nt = 0; nt < 16; ++nt) acc[nt] = (f32x4)0.f;
#pragma unroll
  for (int nt = 0; nt < 16; ++nt)
#pragma unroll
    for (int ks = 0; ks < 8; ++ks) {
      const short8 bfr = *(const short8*)(owp + ((ks * 16 + nt) * 64 + l) * 8);
      acc[nt] = __builtin_amdgcn_mfma_f32_16x16x32_bf16(a[ks], bfr, acc[nt], 0, 0, 0);
    }
#pragma unroll
  for (int nt = 0; nt < 16; ++nt) {
    const int col = nt * 16 + lr;
    const float bv = ob[col];
#pragma unroll
    for (int j = 0; j < 4; ++j)
      out[(size_t)(R0 + w * 16 + lg4 * 4 + j) * 256 + col] = acc[nt][j] + bv;
  }
}

// ---------------------------------------------------------------- launch
extern "C" void kernel_launch(void* const* d_in, const int* in_sizes, int n_in,
                              void* d_out, int out_size, void* d_ws,
                              size_t ws_size, hipStream_t stream) {
  (void)in_sizes; (void)n_in; (void)out_size; (void)ws_size;
  const float* x      = (const float*)d_in[0];
  const float* rpb    = (const float*)d_in[1];
  const float* attn_w = (const float*)d_in[2];
  const float* attn_b = (const float*)d_in[3];
  const float* aln_g  = (const float*)d_in[4];
  const float* aln_b  = (const float*)d_in[5];
  const float* conv_w = (const float*)d_in[6];
  const float* conv_b = (const float*)d_in[7];
  const float* cbn_g  = (const float*)d_in[8];
  const float* cbn_b  = (const float*)d_in[9];
  const float* ci_w1  = (const float*)d_in[10];
  const float* ci_b1  = (const float*)d_in[11];
  const float* ci_bg  = (const float*)d_in[12];
  const float* ci_bb  = (const float*)d_in[13];
  const float* ci_w2  = (const float*)d_in[14];
  const float* ci_b2  = (const float*)d_in[15];
  const float* pr_w   = (const float*)d_in[16];
  const float* pr_b   = (const float*)d_in[17];
  const float* cn_g   = (const float*)d_in[18];
  const float* cn_b   = (const float*)d_in[19];
  const float* qkv_w  = (const float*)d_in[20];
  const float* qkv_b  = (const float*)d_in[21];
  const float* si_w1  = (const float*)d_in[22];
  const float* si_b1  = (const float*)d_in[23];
  const float* si_bg  = (const float*)d_in[24];
  const float* si_bb  = (const float*)d_in[25];
  const float* si_w2  = (const float*)d_in[26];
  const float* si_b2  = (const float*)d_in[27];
  const float* an_g   = (const float*)d_in[28];
  const float* an_b   = (const float*)d_in[29];
  const float* out_w  = (const float*)d_in[30];
  const float* out_b  = (const float*)d_in[31];

  unsigned short* xb    = (unsigned short*)d_ws;          // 33,554,432 e
  unsigned short* xattn = xb + 33554432;                  // 16,777,216 e
  unsigned short* attn  = xattn + 16777216;               // 16,777,216 e
  unsigned short* xpr   = attn + 16777216;                // 16,777,216 e
  float* gpart = (float*)(xpr + 16777216);                // 1,048,576 f
  float* cis   = gpart + 1048576;                         // 4,096 f
  unsigned short* awp  = (unsigned short*)(cis + 4096);   // 32,768 e
  unsigned short* qwp  = awp + 32768;                     // 49,152 e
  unsigned short* prwp = qwp + 49152;                     // 32,768 e
  unsigned short* owp  = prwp + 32768;                    // 65,536 e

  kx_cvt<<<2048, 256, 0, stream>>>((const float4*)x, (ushort4*)xb);
  kpack<<<352, 256, 0, stream>>>(attn_w, qkv_w, pr_w, out_w, awp, qwp, prwp, owp);
  k1_attn_ln<<<2048, 256, 0, stream>>>(xb, awp, attn_b, aln_g, aln_b, xattn);
  k25_conv<<<4096, 256, 0, stream>>>(x, conv_w, conv_b, cbn_g, cbn_b, prwp,
                                     pr_b, xpr, gpart);
  k3_ci<<<32, 128, 0, stream>>>(gpart, ci_w1, ci_b1, ci_bg, ci_bb, ci_w2,
                                ci_b2, cis);
  k4_attn<<<2048, 256, 0, stream>>>(xattn, qwp, qkv_b, cis, rpb, attn);
  k6_tail<<<2048, 256, 0, stream>>>(attn, xpr, si_w1, si_b1, si_bg, si_bb,
                                    si_w2, si_b2, cn_g, cn_b, an_g, an_b,
                                    owp, out_b, (float*)d_out);
}

// Round 4
// 596.125 us; speedup vs baseline: 12.2729x; 1.4277x over previous
//
#include <hip/hip_runtime.h>
#include <math.h>

// MixingAttention forward: bf16 MFMA GEMMs + f16 MFMA attention + f32 epilogues.
// B_=2048 windows, N=64, C=256, Ca=128, NH=8, HD=16, B=32 imgs, h=w=64.

#define BNR 0.9999950000374998f /* 1/sqrt(1+1e-5) */
#define SQRT1_2 0.70710678118654752f

typedef __attribute__((ext_vector_type(8))) short short8;
typedef __attribute__((ext_vector_type(4))) float f32x4;
typedef __attribute__((ext_vector_type(4))) _Float16 half4;

__device__ __forceinline__ float gelu_f(float x) {
  return 0.5f * x * (1.0f + erff(x * SQRT1_2));
}
__device__ __forceinline__ unsigned short f2bf(float f) {
  unsigned int u = __builtin_bit_cast(unsigned int, f);
  u += 0x7fffu + ((u >> 16) & 1u);
  return (unsigned short)(u >> 16);
}
__device__ __forceinline__ float bf2f(unsigned short h) {
  unsigned int u = ((unsigned int)h) << 16;
  return __builtin_bit_cast(float, u);
}
__device__ __forceinline__ void ld8(const unsigned short* p, float* o) {
  const short8 v = *(const short8*)p;
#pragma unroll
  for (int i = 0; i < 8; ++i) o[i] = bf2f((unsigned short)v[i]);
}

// ---------------------------------------------------------------- kx
__global__ __launch_bounds__(256) void kx_cvt(const float4* __restrict__ x,
                                              ushort4* __restrict__ xb) {
  const int n4 = 131072 * 64;
  for (int i = blockIdx.x * 256 + threadIdx.x; i < n4; i += 2048 * 256) {
    const float4 v = x[i];
    ushort4 o;
    o.x = f2bf(v.x); o.y = f2bf(v.y); o.z = f2bf(v.z); o.w = f2bf(v.w);
    xb[i] = o;
  }
}

// ---------------------------------------------------------------- kpack
// dst[(fs*64+l)*8+i] = W[ks*32+(l>>4)*8+i][nt*16+(l&15)], fs=ks*NT+nt.
__global__ __launch_bounds__(256) void kpack(
    const float* __restrict__ aw, const float* __restrict__ qw,
    const float* __restrict__ prw, const float* __restrict__ ow,
    unsigned short* __restrict__ awp, unsigned short* __restrict__ qwp,
    unsigned short* __restrict__ prwp, unsigned short* __restrict__ owp) {
  const int b = blockIdx.x;
  const float* src; unsigned short* dst; int fs, K, N, NT, trans;
  if (b < 64)       { fs = b;       src = aw;  dst = awp;  K = 256; N = 128; NT = 8;  trans = 0; }
  else if (b < 160) { fs = b - 64;  src = qw;  dst = qwp;  K = 128; N = 384; NT = 24; trans = 0; }
  else if (b < 224) { fs = b - 160; src = prw; dst = prwp; K = 256; N = 128; NT = 8;  trans = 1; }
  else              { fs = b - 224; src = ow;  dst = owp;  K = 256; N = 256; NT = 16; trans = 0; }
  const int ks = fs / NT, nt = fs % NT;
  for (int idx = threadIdx.x; idx < 512; idx += 256) {
    const int l = idx >> 3, i = idx & 7;
    const int k = ks * 32 + ((l >> 4) << 3) + i, n = nt * 16 + (l & 15);
    const float v = trans ? src[n * K + k] : src[k * N + n];
    dst[(fs * 64 + l) * 8 + i] = f2bf(v);
  }
}

// ---------------------------------------------------------------- k1
__global__ __launch_bounds__(256) void k1_attn_ln(
    const unsigned short* __restrict__ xb, const unsigned short* __restrict__ awp,
    const float* __restrict__ ab, const float* __restrict__ lg,
    const float* __restrict__ lb, unsigned short* __restrict__ xattn) {
  const int tid = threadIdx.x, w = tid >> 6, l = tid & 63;
  const int lr = l & 15, lg4 = l >> 4;
  const int r0 = blockIdx.x * 64 + w * 16;
  short8 a[8];
  const unsigned short* ap = xb + (size_t)(r0 + lr) * 256 + lg4 * 8;
#pragma unroll
  for (int ks = 0; ks < 8; ++ks) a[ks] = *(const short8*)(ap + ks * 32);
  f32x4 acc[8];
#pragma unroll
  for (int nt = 0; nt < 8; ++nt) acc[nt] = (f32x4)0.f;
#pragma unroll
  for (int nt = 0; nt < 8; ++nt)
#pragma unroll
    for (int ks = 0; ks < 8; ++ks) {
      const short8 bfr = *(const short8*)(awp + ((ks * 8 + nt) * 64 + l) * 8);
      acc[nt] = __builtin_amdgcn_mfma_f32_16x16x32_bf16(a[ks], bfr, acc[nt], 0, 0, 0);
    }
  float bias[8], gam[8], bet[8];
#pragma unroll
  for (int nt = 0; nt < 8; ++nt) {
    const int col = nt * 16 + lr;
    bias[nt] = ab[col]; gam[nt] = lg[col]; bet[nt] = lb[col];
  }
#pragma unroll
  for (int j = 0; j < 4; ++j) {
    float s = 0.f, qq = 0.f;
#pragma unroll
    for (int nt = 0; nt < 8; ++nt) {
      const float v = acc[nt][j] + bias[nt];
      acc[nt][j] = v; s += v; qq += v * v;
    }
    s += __shfl_xor(s, 1); s += __shfl_xor(s, 2);
    s += __shfl_xor(s, 4); s += __shfl_xor(s, 8);
    qq += __shfl_xor(qq, 1); qq += __shfl_xor(qq, 2);
    qq += __shfl_xor(qq, 4); qq += __shfl_xor(qq, 8);
    const float mean = s * (1.f / 128.f);
    const float var = qq * (1.f / 128.f) - mean * mean;
    const float rstd = rsqrtf(var + 1e-5f);
    const int row = r0 + lg4 * 4 + j;
#pragma unroll
    for (int nt = 0; nt < 8; ++nt)
      xattn[(size_t)row * 128 + nt * 16 + lr] =
          f2bf((acc[nt][j] - mean) * rstd * gam[nt] + bet[nt]);
  }
}

// ---------------------------------------------------------------- k25
// Phase1: depthwise 3x3 + BN + GELU from bf16 xb -> gl bf16 LDS + GAP partials.
// Phase2: pr 1x1 via MFMA.
__global__ __launch_bounds__(256) void k25_conv(
    const unsigned short* __restrict__ xb, const float* __restrict__ cw,
    const float* __restrict__ cb, const float* __restrict__ bg,
    const float* __restrict__ bb, const unsigned short* __restrict__ prwp,
    const float* __restrict__ prb, unsigned short* __restrict__ xpr,
    float* __restrict__ gpart) {
  __shared__ unsigned short gl[32][264];
  const int tid = threadIdx.x;
  const int b = blockIdx.x >> 7;
  const int y = (blockIdx.x >> 1) & 63;
  const int xt = (blockIdx.x & 1) * 32;
  {
    const int c = tid;
    float w9[9];
#pragma unroll
    for (int k = 0; k < 9; ++k) w9[k] = cw[c * 9 + k];
    const float cbv = cb[c];
    const float sc = bg[c] * BNR;
    const float sb = bb[c];
    float gsum = 0.f;
    for (int p = 0; p < 32; ++p) {
      const int px = xt + p;
      float s = cbv;
#pragma unroll
      for (int dy = -1; dy <= 1; ++dy) {
        const int yy = y + dy;
        if ((unsigned)yy < 64u) {
#pragma unroll
          for (int dx = -1; dx <= 1; ++dx) {
            const int xx = px + dx;
            if ((unsigned)xx < 64u) {
              const int row = (b * 64 + (yy >> 3) * 8 + (xx >> 3)) * 64 +
                              (yy & 7) * 8 + (xx & 7);
              s = fmaf(w9[(dy + 1) * 3 + dx + 1],
                       bf2f(xb[(size_t)row * 256 + c]), s);
            }
          }
        }
      }
      s = s * sc + sb;
      const float g = gelu_f(s);
      gl[p][c] = f2bf(g);
      gsum += g;
    }
    gpart[(size_t)blockIdx.x * 256 + c] = gsum;
  }
  __syncthreads();
  const int w = tid >> 6, l = tid & 63, lr = l & 15, lg4 = l >> 4;
  const int mr0 = (w & 1) * 16, nt0 = (w >> 1) * 4;
  short8 a[8];
#pragma unroll
  for (int ks = 0; ks < 8; ++ks)
    a[ks] = *(const short8*)&gl[mr0 + lr][ks * 32 + lg4 * 8];
  f32x4 acc[4];
#pragma unroll
  for (int nt = 0; nt < 4; ++nt) acc[nt] = (f32x4)0.f;
#pragma unroll
  for (int nt = 0; nt < 4; ++nt)
#pragma unroll
    for (int ks = 0; ks < 8; ++ks) {
      const short8 bfr =
          *(const short8*)(prwp + ((ks * 8 + nt0 + nt) * 64 + l) * 8);
      acc[nt] = __builtin_amdgcn_mfma_f32_16x16x32_bf16(a[ks], bfr, acc[nt], 0, 0, 0);
    }
#pragma unroll
  for (int nt = 0; nt < 4; ++nt) {
    const int col = (nt0 + nt) * 16 + lr;
    const float bv = prb[col];
#pragma unroll
    for (int j = 0; j < 4; ++j) {
      const int pix = (b * 64 + y) * 64 + xt + mr0 + lg4 * 4 + j;
      xpr[(size_t)pix * 128 + col] = f2bf(acc[nt][j] + bv);
    }
  }
}

// ---------------------------------------------------------------- k3
__global__ __launch_bounds__(128) void k3_ci(
    const float* __restrict__ gp, const float* __restrict__ w1,
    const float* __restrict__ b1, const float* __restrict__ g1,
    const float* __restrict__ bb1, const float* __restrict__ w2,
    const float* __restrict__ b2, float* __restrict__ cis) {
  __shared__ float gm[256];
  __shared__ float c1[32];
  const int b = blockIdx.x, tid = threadIdx.x;
  for (int c = tid; c < 256; c += 128) {
    float s = 0.f;
    for (int p = 0; p < 128; ++p) s += gp[(size_t)(b * 128 + p) * 256 + c];
    gm[c] = s * (1.f / 4096.f);
  }
  __syncthreads();
  if (tid < 32) {
    float s = b1[tid];
    for (int c = 0; c < 256; ++c) s = fmaf(gm[c], w1[tid * 256 + c], s);
    s = s * (g1[tid] * BNR) + bb1[tid];
    c1[tid] = gelu_f(s);
  }
  __syncthreads();
  float s = b2[tid];
#pragma unroll
  for (int i = 0; i < 32; ++i) s = fmaf(c1[i], w2[tid * 32 + i], s);
  cis[b * 128 + tid] = 1.f / (1.f + __expf(-s));
}

// ---------------------------------------------------------------- k4
// qkv GEMM (bf16 MFMA) -> Q/K/VT f16 LDS -> S^T = K·Q^T via mfma 16x16x16f16
// (swapped trick: P^T D-layout == PV A-layout), softmax in-register, PV MFMA.
__global__ __launch_bounds__(256) void k4_attn(
    const unsigned short* __restrict__ xa, const unsigned short* __restrict__ qwp,
    const float* __restrict__ qb, const float* __restrict__ cis,
    const float* __restrict__ rpb, unsigned short* __restrict__ attn) {
  __shared__ _Float16 Qs[64][130];
  __shared__ _Float16 Ks[64][130];
  __shared__ _Float16 VT[128][66];
  __shared__ float bsl[8][226];
  __shared__ float cisl[128];
  __shared__ float qbl[384];
  const int tid = threadIdx.x;
  const int win = blockIdx.x, img = win >> 6;
  for (int i = tid; i < 1800; i += 256) bsl[i & 7][i >> 3] = rpb[i];
  for (int i = tid; i < 128; i += 256) cisl[i] = cis[img * 128 + i];
  for (int i = tid; i < 384; i += 256) qbl[i] = qb[i];
  const int w = tid >> 6, l = tid & 63, lr = l & 15, lg4 = l >> 4;
  // --- qkv GEMM: rows w*16..+15, all 384 cols
  short8 a[4];
  const unsigned short* ap = xa + (size_t)(win * 64 + w * 16 + lr) * 128 + lg4 * 8;
#pragma unroll
  for (int ks = 0; ks < 4; ++ks) a[ks] = *(const short8*)(ap + ks * 32);
  f32x4 acc[24];
#pragma unroll
  for (int nt = 0; nt < 24; ++nt) acc[nt] = (f32x4)0.f;
#pragma unroll
  for (int nt = 0; nt < 24; ++nt)
#pragma unroll
    for (int ks = 0; ks < 4; ++ks) {
      const short8 bfr = *(const short8*)(qwp + ((ks * 24 + nt) * 64 + l) * 8);
      acc[nt] = __builtin_amdgcn_mfma_f32_16x16x32_bf16(a[ks], bfr, acc[nt], 0, 0, 0);
    }
  __syncthreads();  // cisl/qbl/bsl ready
  // --- scatter q/k/v to LDS (f16), applying scale/bias/ci
#pragma unroll
  for (int nt = 0; nt < 24; ++nt) {
    const int col = nt * 16 + lr;
#pragma unroll
    for (int j = 0; j < 4; ++j) {
      const int row = w * 16 + lg4 * 4 + j;
      const float v = acc[nt][j] + qbl[col];
      if (nt < 8) Qs[row][col] = (_Float16)(v * 0.25f);
      else if (nt < 16) Ks[row][col - 128] = (_Float16)v;
      else VT[col - 256][row] = (_Float16)(v * cisl[col - 256]);
    }
  }
  __syncthreads();
  // --- attention: wave w handles heads 2w, 2w+1
  for (int hi = 0; hi < 2; ++hi) {
    const int h = w * 2 + hi;
    half4 aK[4], bQ[4], bV[4];
#pragma unroll
    for (int mt = 0; mt < 4; ++mt)
      aK[mt] = *(const half4*)&Ks[mt * 16 + lr][h * 16 + lg4 * 4];
#pragma unroll
    for (int nt = 0; nt < 4; ++nt)
      bQ[nt] = *(const half4*)&Qs[nt * 16 + lr][h * 16 + lg4 * 4];
#pragma unroll
    for (int kt = 0; kt < 4; ++kt)
      bV[kt] = *(const half4*)&VT[h * 16 + lr][kt * 16 + lg4 * 4];
    f32x4 s[4][4];  // [mt][nt], S^T: row=m(key), col=n(query)
#pragma unroll
    for (int mt = 0; mt < 4; ++mt)
#pragma unroll
      for (int nt = 0; nt < 4; ++nt)
        s[mt][nt] = __builtin_amdgcn_mfma_f32_16x16x16f16(aK[mt], bQ[nt],
                                                          (f32x4)0.f, 0, 0, 0);
    // bias
#pragma unroll
    for (int mt = 0; mt < 4; ++mt) {
      const int m0 = mt * 16 + lg4 * 4;
#pragma unroll
      for (int r = 0; r < 4; ++r) {
        const int m = m0 + r;
        const int my = m >> 3, mxx = m & 7;
#pragma unroll
        for (int nt = 0; nt < 4; ++nt) {
          const int n = nt * 16 + lr;
          s[mt][nt][r] += bsl[h][((n >> 3) - my + 7) * 15 + (n & 7) - mxx + 7];
        }
      }
    }
    // softmax over m per n (in-lane 16 + shfl over lg4 groups)
    float inv[4];
#pragma unroll
    for (int nt = 0; nt < 4; ++nt) {
      float m0 = -1e30f;
#pragma unroll
      for (int mt = 0; mt < 4; ++mt)
#pragma unroll
        for (int r = 0; r < 4; ++r) m0 = fmaxf(m0, s[mt][nt][r]);
      m0 = fmaxf(m0, __shfl_xor(m0, 16));
      m0 = fmaxf(m0, __shfl_xor(m0, 32));
      float d0 = 0.f;
#pragma unroll
      for (int mt = 0; mt < 4; ++mt)
#pragma unroll
        for (int r = 0; r < 4; ++r) {
          const float e = __expf(s[mt][nt][r] - m0);
          s[mt][nt][r] = e;
          d0 += e;
        }
      d0 += __shfl_xor(d0, 16);
      d0 += __shfl_xor(d0, 32);
      inv[nt] = 1.f / d0;
    }
    // pack P (normalized) into PV A-frags: pa[nt][kt] = P[n tile nt][m tile kt]
    half4 pa[4][4];
#pragma unroll
    for (int nt = 0; nt < 4; ++nt)
#pragma unroll
      for (int kt = 0; kt < 4; ++kt) {
        half4 p;
#pragma unroll
        for (int r = 0; r < 4; ++r) p[r] = (_Float16)(s[kt][nt][r] * inv[nt]);
        pa[nt][kt] = p;
      }
    f32x4 o[4];
#pragma unroll
    for (int nt = 0; nt < 4; ++nt) o[nt] = (f32x4)0.f;
#pragma unroll
    for (int nt = 0; nt < 4; ++nt)
#pragma unroll
      for (int kt = 0; kt < 4; ++kt)
        o[nt] = __builtin_amdgcn_mfma_f32_16x16x16f16(pa[nt][kt], bV[kt], o[nt], 0, 0, 0);
#pragma unroll
    for (int nt = 0; nt < 4; ++nt)
#pragma unroll
      for (int r = 0; r < 4; ++r) {
        const int token = win * 64 + nt * 16 + lg4 * 4 + r;
        attn[(size_t)token * 128 + h * 16 + lr] = f2bf(o[nt][r]);
      }
  }
}

// ---------------------------------------------------------------- k6
__global__ __launch_bounds__(256) void k6_tail(
    const unsigned short* __restrict__ attn, const unsigned short* __restrict__ xpr,
    const float* __restrict__ sw1, const float* __restrict__ sb1,
    const float* __restrict__ sgc, const float* __restrict__ sbc,
    const float* __restrict__ sw2, const float* __restrict__ sb2,
    const float* __restrict__ cg, const float* __restrict__ cbb,
    const float* __restrict__ ag, const float* __restrict__ abb,
    const unsigned short* __restrict__ owp, const float* __restrict__ ob,
    float* __restrict__ out) {
  __shared__ unsigned short At[64][264];
  __shared__ float sw1l[16][132];
  __shared__ float s1l[64][17];
  __shared__ float sifl[64];
  __shared__ float statl[64][2];
  const int tid = threadIdx.x;
  const int R0 = blockIdx.x * 64;
  for (int i = tid; i < 1024; i += 256) {
    const int r = i >> 4, cb = (i & 15) * 8;
    *(uint4*)&At[r][cb] = *(const uint4*)&attn[(size_t)(R0 + r) * 128 + cb];
    const int R = R0 + r, win = R >> 6, tt = R & 63;
    const int bimg = win >> 6, wy = (win >> 3) & 7, wx = win & 7;
    const int pix = (bimg * 64 + wy * 8 + (tt >> 3)) * 64 + wx * 8 + (tt & 7);
    *(uint4*)&At[r][128 + cb] = *(const uint4*)&xpr[(size_t)pix * 128 + cb];
  }
  for (int i = tid; i < 2048; i += 256) sw1l[i >> 7][i & 127] = sw1[i];
  __syncthreads();
  {
    const int r = tid >> 2, q = tid & 3;
    float xv[32];
#pragma unroll
    for (int b8 = 0; b8 < 4; ++b8) ld8(&At[r][q * 32 + b8 * 8], xv + b8 * 8);
    float ps = 0.f, pq = 0.f;
#pragma unroll
    for (int j = 0; j < 32; ++j) { ps += xv[j]; pq += xv[j] * xv[j]; }
    ps += __shfl_xor(ps, 1); ps += __shfl_xor(ps, 2);
    pq += __shfl_xor(pq, 1); pq += __shfl_xor(pq, 2);
    if (q == 0) {
      const float mean = ps * (1.f / 128.f);
      const float var = pq * (1.f / 128.f) - mean * mean;
      statl[r][0] = mean;
      statl[r][1] = rsqrtf(var + 1e-5f);
    }
    float part[16];
#pragma unroll
    for (int o = 0; o < 16; ++o) {
      float s = 0.f;
      const float* wr = &sw1l[o][q * 32];
#pragma unroll
      for (int j = 0; j < 32; ++j) s = fmaf(xv[j], wr[j], s);
      part[o] = s;
    }
#pragma unroll
    for (int o = 0; o < 16; ++o) {
      part[o] += __shfl_xor(part[o], 1);
      part[o] += __shfl_xor(part[o], 2);
    }
#pragma unroll
    for (int jo = 0; jo < 4; ++jo) {
      const int o = q * 4 + jo;
      float s = part[o] + sb1[o];
      s = s * (sgc[o] * BNR) + sbc[o];
      s1l[r][o] = gelu_f(s);
    }
  }
  __syncthreads();
  if (tid < 64) {
    float s = sb2[0];
#pragma unroll
    for (int i = 0; i < 16; ++i) s = fmaf(s1l[tid][i], sw2[i], s);
    sifl[tid] = s;
  }
  __syncthreads();
  for (int i = tid; i < 8192; i += 256) {
    const int r = i >> 7, c = i & 127;
    float a = bf2f(At[r][c]);
    a = (a - statl[r][0]) * statl[r][1] * ag[c] + abb[c];
    At[r][c] = f2bf(a);
    const float cv = bf2f(At[r][128 + c]);
    const float g = 1.f / (1.f + __expf(-sifl[r] * cv));
    At[r][128 + c] = f2bf(g * (cg[c] * BNR) + cbb[c]);
  }
  __syncthreads();
  const int w = tid >> 6, l = tid & 63, lr = l & 15, lg4 = l >> 4;
  short8 a[8];
#pragma unroll
  for (int ks = 0; ks < 8; ++ks)
    a[ks] = *(const short8*)&At[w * 16 + lr][ks * 32 + lg4 * 8];
  f32x4 acc[16];
#pragma unroll
  for (int nt = 0; nt < 16; ++nt) acc[nt] = (f32x4)0.f;
#pragma unroll
  for (int nt = 0; nt < 16; ++nt)
#pragma unroll
    for (int ks = 0; ks < 8; ++ks) {
      const short8 bfr = *(const short8*)(owp + ((ks * 16 + nt) * 64 + l) * 8);
      acc[nt] = __builtin_amdgcn_mfma_f32_16x16x32_bf16(a[ks], bfr, acc[nt], 0, 0, 0);
    }
#pragma unroll
  for (int nt = 0; nt < 16; ++nt) {
    const int col = nt * 16 + lr;
    const float bv = ob[col];
#pragma unroll
    for (int j = 0; j < 4; ++j)
      out[(size_t)(R0 + w * 16 + lg4 * 4 + j) * 256 + col] = acc[nt][j] + bv;
  }
}

// ---------------------------------------------------------------- launch
extern "C" void kernel_launch(void* const* d_in, const int* in_sizes, int n_in,
                              void* d_out, int out_size, void* d_ws,
                              size_t ws_size, hipStream_t stream) {
  (void)in_sizes; (void)n_in; (void)out_size; (void)ws_size;
  const float* x      = (const float*)d_in[0];
  const float* rpb    = (const float*)d_in[1];
  const float* attn_w = (const float*)d_in[2];
  const float* attn_b = (const float*)d_in[3];
  const float* aln_g  = (const float*)d_in[4];
  const float* aln_b  = (const float*)d_in[5];
  const float* conv_w = (const float*)d_in[6];
  const float* conv_b = (const float*)d_in[7];
  const float* cbn_g  = (const float*)d_in[8];
  const float* cbn_b  = (const float*)d_in[9];
  const float* ci_w1  = (const float*)d_in[10];
  const float* ci_b1  = (const float*)d_in[11];
  const float* ci_bg  = (const float*)d_in[12];
  const float* ci_bb  = (const float*)d_in[13];
  const float* ci_w2  = (const float*)d_in[14];
  const float* ci_b2  = (const float*)d_in[15];
  const float* pr_w   = (const float*)d_in[16];
  const float* pr_b   = (const float*)d_in[17];
  const float* cn_g   = (const float*)d_in[18];
  const float* cn_b   = (const float*)d_in[19];
  const float* qkv_w  = (const float*)d_in[20];
  const float* qkv_b  = (const float*)d_in[21];
  const float* si_w1  = (const float*)d_in[22];
  const float* si_b1  = (const float*)d_in[23];
  const float* si_bg  = (const float*)d_in[24];
  const float* si_bb  = (const float*)d_in[25];
  const float* si_w2  = (const float*)d_in[26];
  const float* si_b2  = (const float*)d_in[27];
  const float* an_g   = (const float*)d_in[28];
  const float* an_b   = (const float*)d_in[29];
  const float* out_w  = (const float*)d_in[30];
  const float* out_b  = (const float*)d_in[31];

  unsigned short* xb    = (unsigned short*)d_ws;          // 33,554,432 e
  unsigned short* xattn = xb + 33554432;                  // 16,777,216 e
  unsigned short* attn  = xattn + 16777216;               // 16,777,216 e
  unsigned short* xpr   = attn + 16777216;                // 16,777,216 e
  float* gpart = (float*)(xpr + 16777216);                // 1,048,576 f
  float* cis   = gpart + 1048576;                         // 4,096 f
  unsigned short* awp  = (unsigned short*)(cis + 4096);   // 32,768 e
  unsigned short* qwp  = awp + 32768;                     // 49,152 e
  unsigned short* prwp = qwp + 49152;                     // 32,768 e
  unsigned short* owp  = prwp + 32768;                    // 65,536 e

  kx_cvt<<<2048, 256, 0, stream>>>((const float4*)x, (ushort4*)xb);
  kpack<<<352, 256, 0, stream>>>(attn_w, qkv_w, pr_w, out_w, awp, qwp, prwp, owp);
  k1_attn_ln<<<2048, 256, 0, stream>>>(xb, awp, attn_b, aln_g, aln_b, xattn);
  k25_conv<<<4096, 256, 0, stream>>>(xb, conv_w, conv_b, cbn_g, cbn_b, prwp,
                                     pr_b, xpr, gpart);
  k3_ci<<<32, 128, 0, stream>>>(gpart, ci_w1, ci_b1, ci_bg, ci_bb, ci_w2,
                                ci_b2, cis);
  k4_attn<<<2048, 256, 0, stream>>>(xattn, qwp, qkv_b, cis, rpb, attn);
  k6_tail<<<2048, 256, 0, stream>>>(attn, xpr, si_w1, si_b1, si_bg, si_bb,
                                    si_w2, si_b2, cn_g, cn_b, an_g, an_b,
                                    owp, out_b, (float*)d_out);
}

// Round 6
// 357.763 us; speedup vs baseline: 20.4498x; 1.6663x over previous
//
#include <hip/hip_runtime.h>
#include <math.h>

// MixingAttention forward: bf16 MFMA GEMMs + f16 MFMA attention + f32 epilogues.
// B_=2048 windows, N=64, C=256, Ca=128, NH=8, HD=16, B=32 imgs, h=w=64.

#define BNR 0.9999950000374998f /* 1/sqrt(1+1e-5) */
#define SQRT1_2 0.70710678118654752f

typedef __attribute__((ext_vector_type(8))) short short8;
typedef __attribute__((ext_vector_type(4))) float f32x4;
typedef __attribute__((ext_vector_type(4))) _Float16 half4;

__device__ __forceinline__ float gelu_f(float x) {
  return 0.5f * x * (1.0f + erff(x * SQRT1_2));
}
__device__ __forceinline__ unsigned short f2bf(float f) {
  unsigned int u = __builtin_bit_cast(unsigned int, f);
  u += 0x7fffu + ((u >> 16) & 1u);
  return (unsigned short)(u >> 16);
}
__device__ __forceinline__ float bf2f(unsigned short h) {
  unsigned int u = ((unsigned int)h) << 16;
  return __builtin_bit_cast(float, u);
}
__device__ __forceinline__ void ld8(const unsigned short* p, float* o) {
  const short8 v = *(const short8*)p;
#pragma unroll
  for (int i = 0; i < 8; ++i) o[i] = bf2f((unsigned short)v[i]);
}

// Swizzled LDS index for 64x256-ushort tile: 16B chunk ch XOR'd by row&7.
#define ATI(r, ch) (((r) << 8) + ((((ch) ^ ((r)&7))) << 3))

// ---------------------------------------------------------------- kpack
// Pack W[k][n] (or W[n][k] if trans) into MFMA B-frag order:
// dst[(fs*64+l)*8+i] = W[ks*32+(l>>4)*8+i][nt*16+(l&15)], fs=ks*NT+nt.
// Fragment counts: aw 64, qw 96, prw 64, ow 128, sw1 4 -> grid 356.
__global__ __launch_bounds__(256) void kpack(
    const float* __restrict__ aw, const float* __restrict__ qw,
    const float* __restrict__ prw, const float* __restrict__ ow,
    const float* __restrict__ sw1, unsigned short* __restrict__ awp,
    unsigned short* __restrict__ qwp, unsigned short* __restrict__ prwp,
    unsigned short* __restrict__ owp, unsigned short* __restrict__ sw1p) {
  const int b = blockIdx.x;
  const float* src; unsigned short* dst; int fs, K, N, NT, trans;
  if (b < 64)       { fs = b;       src = aw;  dst = awp;  K = 256; N = 128; NT = 8;  trans = 0; }
  else if (b < 160) { fs = b - 64;  src = qw;  dst = qwp;  K = 128; N = 384; NT = 24; trans = 0; }
  else if (b < 224) { fs = b - 160; src = prw; dst = prwp; K = 256; N = 128; NT = 8;  trans = 1; }
  else if (b < 352) { fs = b - 224; src = ow;  dst = owp;  K = 256; N = 256; NT = 16; trans = 0; }
  else              { fs = b - 352; src = sw1; dst = sw1p; K = 128; N = 16;  NT = 1;  trans = 1; }
  const int ks = fs / NT, nt = fs % NT;
  for (int idx = threadIdx.x; idx < 512; idx += 256) {
    const int l = idx >> 3, i = idx & 7;
    const int k = ks * 32 + ((l >> 4) << 3) + i, n = nt * 16 + (l & 15);
    const float v = trans ? src[n * K + k] : src[k * N + n];
    dst[(fs * 64 + l) * 8 + i] = f2bf(v);
  }
}

// ---------------------------------------------------------------- k1
// Reads f32 x, emits xb (bf16 copy) + xattn = bf16(LN(x@aw+ab)).
__global__ __launch_bounds__(256) void k1_attn_ln(
    const float* __restrict__ x, const unsigned short* __restrict__ awp,
    const float* __restrict__ ab, const float* __restrict__ lg,
    const float* __restrict__ lb, unsigned short* __restrict__ xattn,
    unsigned short* __restrict__ xb) {
  const int tid = threadIdx.x, w = tid >> 6, l = tid & 63;
  const int lr = l & 15, lg4 = l >> 4;
  const int r0 = blockIdx.x * 64 + w * 16;
  const float* xp = x + (size_t)(r0 + lr) * 256 + lg4 * 8;
  unsigned short* xbp = xb + (size_t)(r0 + lr) * 256 + lg4 * 8;
  short8 a[8];
#pragma unroll
  for (int ks = 0; ks < 8; ++ks) {
    const float4 f0 = *(const float4*)(xp + ks * 32);
    const float4 f1 = *(const float4*)(xp + ks * 32 + 4);
    short8 av;
    av[0] = f2bf(f0.x); av[1] = f2bf(f0.y); av[2] = f2bf(f0.z); av[3] = f2bf(f0.w);
    av[4] = f2bf(f1.x); av[5] = f2bf(f1.y); av[6] = f2bf(f1.z); av[7] = f2bf(f1.w);
    a[ks] = av;
    *(short8*)(xbp + ks * 32) = av;
  }
  f32x4 acc[8];
#pragma unroll
  for (int nt = 0; nt < 8; ++nt) acc[nt] = (f32x4)0.f;
#pragma unroll
  for (int nt = 0; nt < 8; ++nt)
#pragma unroll
    for (int ks = 0; ks < 8; ++ks) {
      const short8 bfr = *(const short8*)(awp + ((ks * 8 + nt) * 64 + l) * 8);
      acc[nt] = __builtin_amdgcn_mfma_f32_16x16x32_bf16(a[ks], bfr, acc[nt], 0, 0, 0);
    }
  float bias[8], gam[8], bet[8];
#pragma unroll
  for (int nt = 0; nt < 8; ++nt) {
    const int col = nt * 16 + lr;
    bias[nt] = ab[col]; gam[nt] = lg[col]; bet[nt] = lb[col];
  }
#pragma unroll
  for (int j = 0; j < 4; ++j) {
    float s = 0.f, qq = 0.f;
#pragma unroll
    for (int nt = 0; nt < 8; ++nt) {
      const float v = acc[nt][j] + bias[nt];
      acc[nt][j] = v; s += v; qq += v * v;
    }
    s += __shfl_xor(s, 1); s += __shfl_xor(s, 2);
    s += __shfl_xor(s, 4); s += __shfl_xor(s, 8);
    qq += __shfl_xor(qq, 1); qq += __shfl_xor(qq, 2);
    qq += __shfl_xor(qq, 4); qq += __shfl_xor(qq, 8);
    const float mean = s * (1.f / 128.f);
    const float var = qq * (1.f / 128.f) - mean * mean;
    const float rstd = rsqrtf(var + 1e-5f);
    const int row = r0 + lg4 * 4 + j;
#pragma unroll
    for (int nt = 0; nt < 8; ++nt)
      xattn[(size_t)row * 128 + nt * 16 + lr] =
          f2bf((acc[nt][j] - mean) * rstd * gam[nt] + bet[nt]);
  }
}

// ---------------------------------------------------------------- k25
// Phase1: depthwise 3x3 + BN + GELU (chunked sliding-window preload).
// Phase2: pr 1x1 via MFMA.
__global__ __launch_bounds__(256) void k25_conv(
    const unsigned short* __restrict__ xb, const float* __restrict__ cw,
    const float* __restrict__ cb, const float* __restrict__ bg,
    const float* __restrict__ bb, const unsigned short* __restrict__ prwp,
    const float* __restrict__ prb, unsigned short* __restrict__ xpr,
    float* __restrict__ gpart) {
  __shared__ unsigned short gl[32][264];
  const int tid = threadIdx.x;
  const int b = blockIdx.x >> 7;
  const int y = (blockIdx.x >> 1) & 63;
  const int xt = (blockIdx.x & 1) * 32;
  {
    const int c = tid;
    float w9[9];
#pragma unroll
    for (int k = 0; k < 9; ++k) w9[k] = cw[c * 9 + k];
    const float cbv = cb[c];
    const float sc = bg[c] * BNR;
    const float sb = bb[c];
    float gsum = 0.f;
#pragma unroll
    for (int cc = 0; cc < 4; ++cc) {
      const int px0 = xt + cc * 8;
      float v[3][10];
#pragma unroll
      for (int dy = 0; dy < 3; ++dy) {
        const int yy = y + dy - 1;
        const bool vy = (unsigned)yy < 64u;
#pragma unroll
        for (int q = 0; q < 10; ++q) {
          const int xx = px0 - 1 + q;
          float val = 0.f;
          if (vy && (unsigned)xx < 64u) {
            const int row = (b * 64 + (yy >> 3) * 8 + (xx >> 3)) * 64 +
                            (yy & 7) * 8 + (xx & 7);
            val = bf2f(xb[(size_t)row * 256 + c]);
          }
          v[dy][q] = val;
        }
      }
#pragma unroll
      for (int p = 0; p < 8; ++p) {
        float s = cbv;
#pragma unroll
        for (int dy = 0; dy < 3; ++dy)
#pragma unroll
          for (int dx = 0; dx < 3; ++dx)
            s = fmaf(w9[dy * 3 + dx], v[dy][p + dx], s);
        s = s * sc + sb;
        const float g = gelu_f(s);
        gl[cc * 8 + p][c] = f2bf(g);
        gsum += g;
      }
    }
    gpart[(size_t)blockIdx.x * 256 + c] = gsum;
  }
  __syncthreads();
  const int w = tid >> 6, l = tid & 63, lr = l & 15, lg4 = l >> 4;
  const int mr0 = (w & 1) * 16, nt0 = (w >> 1) * 4;
  short8 a[8];
#pragma unroll
  for (int ks = 0; ks < 8; ++ks)
    a[ks] = *(const short8*)&gl[mr0 + lr][ks * 32 + lg4 * 8];
  f32x4 acc[4];
#pragma unroll
  for (int nt = 0; nt < 4; ++nt) acc[nt] = (f32x4)0.f;
#pragma unroll
  for (int nt = 0; nt < 4; ++nt)
#pragma unroll
    for (int ks = 0; ks < 8; ++ks) {
      const short8 bfr =
          *(const short8*)(prwp + ((ks * 8 + nt0 + nt) * 64 + l) * 8);
      acc[nt] = __builtin_amdgcn_mfma_f32_16x16x32_bf16(a[ks], bfr, acc[nt], 0, 0, 0);
    }
#pragma unroll
  for (int nt = 0; nt < 4; ++nt) {
    const int col = (nt0 + nt) * 16 + lr;
    const float bv = prb[col];
#pragma unroll
    for (int j = 0; j < 4; ++j) {
      const int pix = (b * 64 + y) * 64 + xt + mr0 + lg4 * 4 + j;
      xpr[(size_t)pix * 128 + col] = f2bf(acc[nt][j] + bv);
    }
  }
}

// ---------------------------------------------------------------- k3
__global__ __launch_bounds__(128) void k3_ci(
    const float* __restrict__ gp, const float* __restrict__ w1,
    const float* __restrict__ b1, const float* __restrict__ g1,
    const float* __restrict__ bb1, const float* __restrict__ w2,
    const float* __restrict__ b2, float* __restrict__ cis) {
  __shared__ float gm[256];
  __shared__ float c1[32];
  const int b = blockIdx.x, tid = threadIdx.x;
  for (int c = tid; c < 256; c += 128) {
    float s = 0.f;
    for (int p = 0; p < 128; ++p) s += gp[(size_t)(b * 128 + p) * 256 + c];
    gm[c] = s * (1.f / 4096.f);
  }
  __syncthreads();
  if (tid < 32) {
    float s = b1[tid];
    for (int c = 0; c < 256; ++c) s = fmaf(gm[c], w1[tid * 256 + c], s);
    s = s * (g1[tid] * BNR) + bb1[tid];
    c1[tid] = gelu_f(s);
  }
  __syncthreads();
  float s = b2[tid];
#pragma unroll
  for (int i = 0; i < 32; ++i) s = fmaf(c1[i], w2[tid * 32 + i], s);
  cis[b * 128 + tid] = 1.f / (1.f + __expf(-s));
}

// ---------------------------------------------------------------- k4
// qkv GEMM (bf16 MFMA) -> Q/K/VT f16 LDS -> S^T = K·Q^T via mfma 16x16x16f16
// (swapped trick: P^T D-layout == PV A-layout), softmax in-register, PV MFMA.
__global__ __launch_bounds__(256) void k4_attn(
    const unsigned short* __restrict__ xa, const unsigned short* __restrict__ qwp,
    const float* __restrict__ qb, const float* __restrict__ cis,
    const float* __restrict__ rpb, unsigned short* __restrict__ attn) {
  __shared__ _Float16 Qs[64][130];
  __shared__ _Float16 Ks[64][130];
  __shared__ _Float16 VT[128][66];
  __shared__ float bsl[8][226];
  __shared__ float cisl[128];
  __shared__ float qbl[384];
  const int tid = threadIdx.x;
  const int win = blockIdx.x, img = win >> 6;
  for (int i = tid; i < 1800; i += 256) bsl[i & 7][i >> 3] = rpb[i];
  for (int i = tid; i < 128; i += 256) cisl[i] = cis[img * 128 + i];
  for (int i = tid; i < 384; i += 256) qbl[i] = qb[i];
  const int w = tid >> 6, l = tid & 63, lr = l & 15, lg4 = l >> 4;
  short8 a[4];
  const unsigned short* ap = xa + (size_t)(win * 64 + w * 16 + lr) * 128 + lg4 * 8;
#pragma unroll
  for (int ks = 0; ks < 4; ++ks) a[ks] = *(const short8*)(ap + ks * 32);
  f32x4 acc[24];
#pragma unroll
  for (int nt = 0; nt < 24; ++nt) acc[nt] = (f32x4)0.f;
#pragma unroll
  for (int nt = 0; nt < 24; ++nt)
#pragma unroll
    for (int ks = 0; ks < 4; ++ks) {
      const short8 bfr = *(const short8*)(qwp + ((ks * 24 + nt) * 64 + l) * 8);
      acc[nt] = __builtin_amdgcn_mfma_f32_16x16x32_bf16(a[ks], bfr, acc[nt], 0, 0, 0);
    }
  __syncthreads();  // cisl/qbl/bsl ready
#pragma unroll
  for (int nt = 0; nt < 24; ++nt) {
    const int col = nt * 16 + lr;
#pragma unroll
    for (int j = 0; j < 4; ++j) {
      const int row = w * 16 + lg4 * 4 + j;
      const float v = acc[nt][j] + qbl[col];
      if (nt < 8) Qs[row][col] = (_Float16)(v * 0.25f);
      else if (nt < 16) Ks[row][col - 128] = (_Float16)v;
      else VT[col - 256][row] = (_Float16)(v * cisl[col - 256]);
    }
  }
  __syncthreads();
  for (int hi = 0; hi < 2; ++hi) {
    const int h = w * 2 + hi;
    half4 aK[4], bQ[4], bV[4];
#pragma unroll
    for (int mt = 0; mt < 4; ++mt)
      aK[mt] = *(const half4*)&Ks[mt * 16 + lr][h * 16 + lg4 * 4];
#pragma unroll
    for (int nt = 0; nt < 4; ++nt)
      bQ[nt] = *(const half4*)&Qs[nt * 16 + lr][h * 16 + lg4 * 4];
#pragma unroll
    for (int kt = 0; kt < 4; ++kt)
      bV[kt] = *(const half4*)&VT[h * 16 + lr][kt * 16 + lg4 * 4];
    f32x4 s[4][4];
#pragma unroll
    for (int mt = 0; mt < 4; ++mt)
#pragma unroll
      for (int nt = 0; nt < 4; ++nt)
        s[mt][nt] = __builtin_amdgcn_mfma_f32_16x16x16f16(aK[mt], bQ[nt],
                                                          (f32x4)0.f, 0, 0, 0);
#pragma unroll
    for (int mt = 0; mt < 4; ++mt) {
      const int m0 = mt * 16 + lg4 * 4;
#pragma unroll
      for (int r = 0; r < 4; ++r) {
        const int m = m0 + r;
        const int my = m >> 3, mxx = m & 7;
#pragma unroll
        for (int nt = 0; nt < 4; ++nt) {
          const int n = nt * 16 + lr;
          s[mt][nt][r] += bsl[h][((n >> 3) - my + 7) * 15 + (n & 7) - mxx + 7];
        }
      }
    }
    float inv[4];
#pragma unroll
    for (int nt = 0; nt < 4; ++nt) {
      float m0 = -1e30f;
#pragma unroll
      for (int mt = 0; mt < 4; ++mt)
#pragma unroll
        for (int r = 0; r < 4; ++r) m0 = fmaxf(m0, s[mt][nt][r]);
      m0 = fmaxf(m0, __shfl_xor(m0, 16));
      m0 = fmaxf(m0, __shfl_xor(m0, 32));
      float d0 = 0.f;
#pragma unroll
      for (int mt = 0; mt < 4; ++mt)
#pragma unroll
        for (int r = 0; r < 4; ++r) {
          const float e = __expf(s[mt][nt][r] - m0);
          s[mt][nt][r] = e;
          d0 += e;
        }
      d0 += __shfl_xor(d0, 16);
      d0 += __shfl_xor(d0, 32);
      inv[nt] = 1.f / d0;
    }
    half4 pa[4][4];
#pragma unroll
    for (int nt = 0; nt < 4; ++nt)
#pragma unroll
      for (int kt = 0; kt < 4; ++kt) {
        half4 p;
#pragma unroll
        for (int r = 0; r < 4; ++r) p[r] = (_Float16)(s[kt][nt][r] * inv[nt]);
        pa[nt][kt] = p;
      }
    f32x4 o[4];
#pragma unroll
    for (int nt = 0; nt < 4; ++nt) o[nt] = (f32x4)0.f;
#pragma unroll
    for (int nt = 0; nt < 4; ++nt)
#pragma unroll
      for (int kt = 0; kt < 4; ++kt)
        o[nt] = __builtin_amdgcn_mfma_f32_16x16x16f16(pa[nt][kt], bV[kt], o[nt], 0, 0, 0);
#pragma unroll
    for (int nt = 0; nt < 4; ++nt)
#pragma unroll
      for (int r = 0; r < 4; ++r) {
        const int token = win * 64 + nt * 16 + lg4 * 4 + r;
        attn[(size_t)token * 128 + h * 16 + lr] = f2bf(o[nt][r]);
      }
  }
}

// ---------------------------------------------------------------- k6
// Swizzled At tile; LN stats; si-MLP via MFMA; gating; final GEMM via MFMA.
__global__ __launch_bounds__(256) void k6_tail(
    const unsigned short* __restrict__ attn, const unsigned short* __restrict__ xpr,
    const unsigned short* __restrict__ sw1p, const float* __restrict__ sb1,
    const float* __restrict__ sgc, const float* __restrict__ sbc,
    const float* __restrict__ sw2, const float* __restrict__ sb2,
    const float* __restrict__ cg, const float* __restrict__ cbb,
    const float* __restrict__ ag, const float* __restrict__ abb,
    const unsigned short* __restrict__ owp, const float* __restrict__ ob,
    float* __restrict__ out) {
  __shared__ unsigned short At[64 * 256];
  __shared__ float sifl[64];
  __shared__ float statl[64][2];
  const int tid = threadIdx.x;
  const int R0 = blockIdx.x * 64;
  const int w = tid >> 6, l = tid & 63, lr = l & 15, lg4 = l >> 4;
  for (int i = tid; i < 1024; i += 256) {
    const int r = i >> 4, c16 = i & 15;
    *(uint4*)&At[ATI(r, c16)] =
        *(const uint4*)&attn[(size_t)(R0 + r) * 128 + c16 * 8];
    const int R = R0 + r, win = R >> 6, tt = R & 63;
    const int bimg = win >> 6, wy = (win >> 3) & 7, wx = win & 7;
    const int pix = (bimg * 64 + wy * 8 + (tt >> 3)) * 64 + wx * 8 + (tt & 7);
    *(uint4*)&At[ATI(r, 16 + c16)] =
        *(const uint4*)&xpr[(size_t)pix * 128 + c16 * 8];
  }
  __syncthreads();
  // LN stats over attn half
  {
    const int r = tid >> 2, q = tid & 3;
    float xv[32];
#pragma unroll
    for (int b8 = 0; b8 < 4; ++b8) ld8(&At[ATI(r, q * 4 + b8)], xv + b8 * 8);
    float ps = 0.f, pq = 0.f;
#pragma unroll
    for (int j = 0; j < 32; ++j) { ps += xv[j]; pq += xv[j] * xv[j]; }
    ps += __shfl_xor(ps, 1); ps += __shfl_xor(ps, 2);
    pq += __shfl_xor(pq, 1); pq += __shfl_xor(pq, 2);
    if (q == 0) {
      const float mean = ps * (1.f / 128.f);
      const float var = pq * (1.f / 128.f) - mean * mean;
      statl[r][0] = mean;
      statl[r][1] = rsqrtf(var + 1e-5f);
    }
  }
  // si MLP via MFMA on raw attn half: (16 rows x 128) @ (128 x 16)
  {
    const int row = w * 16 + lr;
    f32x4 sa = (f32x4)0.f;
#pragma unroll
    for (int ks = 0; ks < 4; ++ks) {
      const short8 a4 = *(const short8*)&At[ATI(row, ks * 4 + lg4)];
      const short8 bfr = *(const short8*)(sw1p + (ks * 64 + l) * 8);
      sa = __builtin_amdgcn_mfma_f32_16x16x32_bf16(a4, bfr, sa, 0, 0, 0);
    }
    const float sb1v = sb1[lr], g1v = sgc[lr] * BNR, b1v = sbc[lr];
    const float w2v = sw2[lr], sb2v = sb2[0];
#pragma unroll
    for (int j = 0; j < 4; ++j) {
      float s = (sa[j] + sb1v) * g1v + b1v;
      float p = gelu_f(s) * w2v;
      p += __shfl_xor(p, 1); p += __shfl_xor(p, 2);
      p += __shfl_xor(p, 4); p += __shfl_xor(p, 8);
      if (lr == 0) sifl[w * 16 + lg4 * 4 + j] = p + sb2v;
    }
  }
  __syncthreads();
  // gating + LN apply (per-thread fixed column c)
  {
    const int c = tid & 127;
    const float agv = ag[c], abbv = abb[c];
    const float cgv = cg[c] * BNR, cbbv = cbb[c];
#pragma unroll
    for (int k = 0; k < 32; ++k) {
      const int r = (tid >> 7) + k * 2;
      const int ia = ATI(r, c >> 3) + (c & 7);
      const int ic = ATI(r, 16 + (c >> 3)) + (c & 7);
      float a = bf2f(At[ia]);
      a = (a - statl[r][0]) * statl[r][1] * agv + abbv;
      At[ia] = f2bf(a);
      const float cv = bf2f(At[ic]);
      const float g = 1.f / (1.f + __expf(-sifl[r] * cv));
      At[ic] = f2bf(g * cgv + cbbv);
    }
  }
  __syncthreads();
  // final GEMM (64 x 256) @ (256 x 256)
  const int row = w * 16 + lr;
  short8 a[8];
#pragma unroll
  for (int ks = 0; ks < 8; ++ks)
    a[ks] = *(const short8*)&At[ATI(row, ks * 4 + lg4)];
  f32x4 acc[16];
#pragma unroll
  for (int nt = 0; nt < 16; ++nt) acc[nt] = (f32x4)0.f;
#pragma unroll
  for (int nt = 0; nt < 16; ++nt)
#pragma unroll
    for (int ks = 0; ks < 8; ++ks) {
      const short8 bfr = *(const short8*)(owp + ((ks * 16 + nt) * 64 + l) * 8);
      acc[nt] = __builtin_amdgcn_mfma_f32_16x16x32_bf16(a[ks], bfr, acc[nt], 0, 0, 0);
    }
#pragma unroll
  for (int nt = 0; nt < 16; ++nt) {
    const int col = nt * 16 + lr;
    const float bv = ob[col];
#pragma unroll
    for (int j = 0; j < 4; ++j)
      out[(size_t)(R0 + w * 16 + lg4 * 4 + j) * 256 + col] = acc[nt][j] + bv;
  }
}

// ---------------------------------------------------------------- launch
extern "C" void kernel_launch(void* const* d_in, const int* in_sizes, int n_in,
                              void* d_out, int out_size, void* d_ws,
                              size_t ws_size, hipStream_t stream) {
  (void)in_sizes; (void)n_in; (void)out_size; (void)ws_size;
  const float* x      = (const float*)d_in[0];
  const float* rpb    = (const float*)d_in[1];
  const float* attn_w = (const float*)d_in[2];
  const float* attn_b = (const float*)d_in[3];
  const float* aln_g  = (const float*)d_in[4];
  const float* aln_b  = (const float*)d_in[5];
  const float* conv_w = (const float*)d_in[6];
  const float* conv_b = (const float*)d_in[7];
  const float* cbn_g  = (const float*)d_in[8];
  const float* cbn_b  = (const float*)d_in[9];
  const float* ci_w1  = (const float*)d_in[10];
  const float* ci_b1  = (const float*)d_in[11];
  const float* ci_bg  = (const float*)d_in[12];
  const float* ci_bb  = (const float*)d_in[13];
  const float* ci_w2  = (const float*)d_in[14];
  const float* ci_b2  = (const float*)d_in[15];
  const float* pr_w   = (const float*)d_in[16];
  const float* pr_b   = (const float*)d_in[17];
  const float* cn_g   = (const float*)d_in[18];
  const float* cn_b   = (const float*)d_in[19];
  const float* qkv_w  = (const float*)d_in[20];
  const float* qkv_b  = (const float*)d_in[21];
  const float* si_w1  = (const float*)d_in[22];
  const float* si_b1  = (const float*)d_in[23];
  const float* si_bg  = (const float*)d_in[24];
  const float* si_bb  = (const float*)d_in[25];
  const float* si_w2  = (const float*)d_in[26];
  const float* si_b2  = (const float*)d_in[27];
  const float* an_g   = (const float*)d_in[28];
  const float* an_b   = (const float*)d_in[29];
  const float* out_w  = (const float*)d_in[30];
  const float* out_b  = (const float*)d_in[31];

  unsigned short* xb    = (unsigned short*)d_ws;          // 33,554,432 e
  unsigned short* xattn = xb + 33554432;                  // 16,777,216 e
  unsigned short* attn  = xattn + 16777216;               // 16,777,216 e
  unsigned short* xpr   = attn + 16777216;                // 16,777,216 e
  float* gpart = (float*)(xpr + 16777216);                // 1,048,576 f
  float* cis   = gpart + 1048576;                         // 4,096 f
  unsigned short* awp  = (unsigned short*)(cis + 4096);   // 32,768 e
  unsigned short* qwp  = awp + 32768;                     // 49,152 e
  unsigned short* prwp = qwp + 49152;                     // 32,768 e
  unsigned short* owp  = prwp + 32768;                    // 65,536 e
  unsigned short* sw1p = owp + 65536;                     // 2,048 e

  kpack<<<356, 256, 0, stream>>>(attn_w, qkv_w, pr_w, out_w, si_w1,
                                 awp, qwp, prwp, owp, sw1p);
  k1_attn_ln<<<2048, 256, 0, stream>>>(x, awp, attn_b, aln_g, aln_b, xattn, xb);
  k25_conv<<<4096, 256, 0, stream>>>(xb, conv_w, conv_b, cbn_g, cbn_b, prwp,
                                     pr_b, xpr, gpart);
  k3_ci<<<32, 128, 0, stream>>>(gpart, ci_w1, ci_b1, ci_bg, ci_bb, ci_w2,
                                ci_b2, cis);
  k4_attn<<<2048, 256, 0, stream>>>(xattn, qwp, qkv_b, cis, rpb, attn);
  k6_tail<<<2048, 256, 0, stream>>>(attn, xpr, sw1p, si_b1, si_bg, si_bb,
                                    si_w2, si_b2, cn_g, cn_b, an_g, an_b,
                                    owp, out_b, (float*)d_out);
}

// Round 7
// 329.939 us; speedup vs baseline: 22.1743x; 1.0843x over previous
//
#include <hip/hip_runtime.h>
#include <math.h>

// MixingAttention forward: bf16 MFMA GEMMs + f16 MFMA attention + f32 epilogues.
// B_=2048 windows, N=64, C=256, Ca=128, NH=8, HD=16, B=32 imgs, h=w=64.

#define BNR 0.9999950000374998f /* 1/sqrt(1+1e-5) */
#define SQRT1_2 0.70710678118654752f

typedef __attribute__((ext_vector_type(8))) short short8;
typedef __attribute__((ext_vector_type(4))) float f32x4;
typedef __attribute__((ext_vector_type(4))) _Float16 half4;

__device__ __forceinline__ float gelu_f(float x) {
  return 0.5f * x * (1.0f + erff(x * SQRT1_2));
}
__device__ __forceinline__ unsigned short f2bf(float f) {
  unsigned int u = __builtin_bit_cast(unsigned int, f);
  u += 0x7fffu + ((u >> 16) & 1u);
  return (unsigned short)(u >> 16);
}
__device__ __forceinline__ float bf2f(unsigned short h) {
  unsigned int u = ((unsigned int)h) << 16;
  return __builtin_bit_cast(float, u);
}
__device__ __forceinline__ void ld8(const unsigned short* p, float* o) {
  const short8 v = *(const short8*)p;
#pragma unroll
  for (int i = 0; i < 8; ++i) o[i] = bf2f((unsigned short)v[i]);
}

// Swizzled LDS index for 64x256-ushort tile: 16B chunk ch XOR'd by row&7.
#define ATI(r, ch) (((r) << 8) + ((((ch) ^ ((r)&7))) << 3))

// ---------------------------------------------------------------- kpack
// Pack W[k][n] (or W[n][k] if trans) into MFMA B-frag order:
// dst[(fs*64+l)*8+i] = W[ks*32+(l>>4)*8+i][nt*16+(l&15)], fs=ks*NT+nt.
// Fragment counts: aw 64, qw 96, prw 64, ow 128, sw1 4 -> grid 356.
__global__ __launch_bounds__(256) void kpack(
    const float* __restrict__ aw, const float* __restrict__ qw,
    const float* __restrict__ prw, const float* __restrict__ ow,
    const float* __restrict__ sw1, unsigned short* __restrict__ awp,
    unsigned short* __restrict__ qwp, unsigned short* __restrict__ prwp,
    unsigned short* __restrict__ owp, unsigned short* __restrict__ sw1p) {
  const int b = blockIdx.x;
  const float* src; unsigned short* dst; int fs, K, N, NT, trans;
  if (b < 64)       { fs = b;       src = aw;  dst = awp;  K = 256; N = 128; NT = 8;  trans = 0; }
  else if (b < 160) { fs = b - 64;  src = qw;  dst = qwp;  K = 128; N = 384; NT = 24; trans = 0; }
  else if (b < 224) { fs = b - 160; src = prw; dst = prwp; K = 256; N = 128; NT = 8;  trans = 1; }
  else if (b < 352) { fs = b - 224; src = ow;  dst = owp;  K = 256; N = 256; NT = 16; trans = 0; }
  else              { fs = b - 352; src = sw1; dst = sw1p; K = 128; N = 16;  NT = 1;  trans = 1; }
  const int ks = fs / NT, nt = fs % NT;
  for (int idx = threadIdx.x; idx < 512; idx += 256) {
    const int l = idx >> 3, i = idx & 7;
    const int k = ks * 32 + ((l >> 4) << 3) + i, n = nt * 16 + (l & 15);
    const float v = trans ? src[n * K + k] : src[k * N + n];
    dst[(fs * 64 + l) * 8 + i] = f2bf(v);
  }
}

// ---------------------------------------------------------------- k1
// Reads f32 x, emits xb (bf16 copy) + xattn = bf16(LN(x@aw+ab)).
__global__ __launch_bounds__(256) void k1_attn_ln(
    const float* __restrict__ x, const unsigned short* __restrict__ awp,
    const float* __restrict__ ab, const float* __restrict__ lg,
    const float* __restrict__ lb, unsigned short* __restrict__ xattn,
    unsigned short* __restrict__ xb) {
  const int tid = threadIdx.x, w = tid >> 6, l = tid & 63;
  const int lr = l & 15, lg4 = l >> 4;
  const int r0 = blockIdx.x * 64 + w * 16;
  const float* xp = x + (size_t)(r0 + lr) * 256 + lg4 * 8;
  unsigned short* xbp = xb + (size_t)(r0 + lr) * 256 + lg4 * 8;
  short8 a[8];
#pragma unroll
  for (int ks = 0; ks < 8; ++ks) {
    const float4 f0 = *(const float4*)(xp + ks * 32);
    const float4 f1 = *(const float4*)(xp + ks * 32 + 4);
    short8 av;
    av[0] = f2bf(f0.x); av[1] = f2bf(f0.y); av[2] = f2bf(f0.z); av[3] = f2bf(f0.w);
    av[4] = f2bf(f1.x); av[5] = f2bf(f1.y); av[6] = f2bf(f1.z); av[7] = f2bf(f1.w);
    a[ks] = av;
    *(short8*)(xbp + ks * 32) = av;
  }
  f32x4 acc[8];
#pragma unroll
  for (int nt = 0; nt < 8; ++nt) acc[nt] = (f32x4)0.f;
#pragma unroll
  for (int nt = 0; nt < 8; ++nt)
#pragma unroll
    for (int ks = 0; ks < 8; ++ks) {
      const short8 bfr = *(const short8*)(awp + ((ks * 8 + nt) * 64 + l) * 8);
      acc[nt] = __builtin_amdgcn_mfma_f32_16x16x32_bf16(a[ks], bfr, acc[nt], 0, 0, 0);
    }
  float bias[8], gam[8], bet[8];
#pragma unroll
  for (int nt = 0; nt < 8; ++nt) {
    const int col = nt * 16 + lr;
    bias[nt] = ab[col]; gam[nt] = lg[col]; bet[nt] = lb[col];
  }
#pragma unroll
  for (int j = 0; j < 4; ++j) {
    float s = 0.f, qq = 0.f;
#pragma unroll
    for (int nt = 0; nt < 8; ++nt) {
      const float v = acc[nt][j] + bias[nt];
      acc[nt][j] = v; s += v; qq += v * v;
    }
    s += __shfl_xor(s, 1); s += __shfl_xor(s, 2);
    s += __shfl_xor(s, 4); s += __shfl_xor(s, 8);
    qq += __shfl_xor(qq, 1); qq += __shfl_xor(qq, 2);
    qq += __shfl_xor(qq, 4); qq += __shfl_xor(qq, 8);
    const float mean = s * (1.f / 128.f);
    const float var = qq * (1.f / 128.f) - mean * mean;
    const float rstd = rsqrtf(var + 1e-5f);
    const int row = r0 + lg4 * 4 + j;
#pragma unroll
    for (int nt = 0; nt < 8; ++nt)
      xattn[(size_t)row * 128 + nt * 16 + lr] =
          f2bf((acc[nt][j] - mean) * rstd * gam[nt] + bet[nt]);
  }
}

// ---------------------------------------------------------------- k25
// Phase1: depthwise 3x3 + BN + GELU, lane = 4 channels (ushort4 taps),
// wave = 8 pixels (two 4-px sliding-window subchunks).
// Phase2: pr 1x1 via MFMA.
__global__ __launch_bounds__(256) void k25_conv(
    const unsigned short* __restrict__ xb, const float* __restrict__ cw,
    const float* __restrict__ cb, const float* __restrict__ bg,
    const float* __restrict__ bb, const unsigned short* __restrict__ prwp,
    const float* __restrict__ prb, unsigned short* __restrict__ xpr,
    float* __restrict__ gpart) {
  __shared__ unsigned short gl[32][264];
  const int tid = threadIdx.x;
  const int b = blockIdx.x >> 7;
  const int y = (blockIdx.x >> 1) & 63;
  const int xt = (blockIdx.x & 1) * 32;
  const int w = tid >> 6, l = tid & 63;
  {
    const int c0 = l << 2;
    float4 w9[9];
#pragma unroll
    for (int k = 0; k < 9; ++k) {
      w9[k].x = cw[(c0 + 0) * 9 + k];
      w9[k].y = cw[(c0 + 1) * 9 + k];
      w9[k].z = cw[(c0 + 2) * 9 + k];
      w9[k].w = cw[(c0 + 3) * 9 + k];
    }
    const float4 cbv = *(const float4*)&cb[c0];
    float4 scv = *(const float4*)&bg[c0];
    scv.x *= BNR; scv.y *= BNR; scv.z *= BNR; scv.w *= BNR;
    const float4 sbv = *(const float4*)&bb[c0];
    float4 gsum = make_float4(0.f, 0.f, 0.f, 0.f);
    const int px0 = xt + w * 8;
#pragma unroll
    for (int sc2 = 0; sc2 < 2; ++sc2) {
      const int p0 = px0 + sc2 * 4;
      float4 v[3][6];
#pragma unroll
      for (int dy = 0; dy < 3; ++dy) {
        const int yy = y + dy - 1;
        const bool vy = (unsigned)yy < 64u;
        const int ybase = vy ? ((b * 64 + (yy >> 3) * 8) * 64 + (yy & 7) * 8) : 0;
#pragma unroll
        for (int q = 0; q < 6; ++q) {
          const int xx = p0 - 1 + q;
          float4 f = make_float4(0.f, 0.f, 0.f, 0.f);
          if (vy && (unsigned)xx < 64u) {
            const int row = ybase + (xx >> 3) * 64 + (xx & 7);
            const ushort4 u = *(const ushort4*)&xb[(size_t)row * 256 + c0];
            f.x = bf2f(u.x); f.y = bf2f(u.y); f.z = bf2f(u.z); f.w = bf2f(u.w);
          }
          v[dy][q] = f;
        }
      }
#pragma unroll
      for (int p = 0; p < 4; ++p) {
        float4 s = cbv;
#pragma unroll
        for (int dy = 0; dy < 3; ++dy)
#pragma unroll
          for (int dx = 0; dx < 3; ++dx) {
            const float wv_x = ((const float*)&w9[dy * 3 + dx])[0];
            const float4 wv = w9[dy * 3 + dx];
            const float4 vv = v[dy][p + dx];
            s.x = fmaf(wv.x, vv.x, s.x);
            s.y = fmaf(wv.y, vv.y, s.y);
            s.z = fmaf(wv.z, vv.z, s.z);
            s.w = fmaf(wv.w, vv.w, s.w);
            (void)wv_x;
          }
        s.x = s.x * scv.x + sbv.x; s.y = s.y * scv.y + sbv.y;
        s.z = s.z * scv.z + sbv.z; s.w = s.w * scv.w + sbv.w;
        const float g0 = gelu_f(s.x), g1 = gelu_f(s.y);
        const float g2 = gelu_f(s.z), g3 = gelu_f(s.w);
        ushort4 pk;
        pk.x = f2bf(g0); pk.y = f2bf(g1); pk.z = f2bf(g2); pk.w = f2bf(g3);
        *(ushort4*)&gl[w * 8 + sc2 * 4 + p][c0] = pk;
        gsum.x += g0; gsum.y += g1; gsum.z += g2; gsum.w += g3;
      }
    }
    *(float4*)&gpart[(size_t)blockIdx.x * 256 + c0] = gsum;
  }
  __syncthreads();
  const int lr = l & 15, lg4 = l >> 4;
  const int mr0 = (w & 1) * 16, nt0 = (w >> 1) * 4;
  short8 a[8];
#pragma unroll
  for (int ks = 0; ks < 8; ++ks)
    a[ks] = *(const short8*)&gl[mr0 + lr][ks * 32 + lg4 * 8];
  f32x4 acc[4];
#pragma unroll
  for (int nt = 0; nt < 4; ++nt) acc[nt] = (f32x4)0.f;
#pragma unroll
  for (int nt = 0; nt < 4; ++nt)
#pragma unroll
    for (int ks = 0; ks < 8; ++ks) {
      const short8 bfr =
          *(const short8*)(prwp + ((ks * 8 + nt0 + nt) * 64 + l) * 8);
      acc[nt] = __builtin_amdgcn_mfma_f32_16x16x32_bf16(a[ks], bfr, acc[nt], 0, 0, 0);
    }
#pragma unroll
  for (int nt = 0; nt < 4; ++nt) {
    const int col = (nt0 + nt) * 16 + lr;
    const float bv = prb[col];
#pragma unroll
    for (int j = 0; j < 4; ++j) {
      const int pix = (b * 64 + y) * 64 + xt + mr0 + lg4 * 4 + j;
      xpr[(size_t)pix * 128 + col] = f2bf(acc[nt][j] + bv);
    }
  }
}

// ---------------------------------------------------------------- k3
__global__ __launch_bounds__(128) void k3_ci(
    const float* __restrict__ gp, const float* __restrict__ w1,
    const float* __restrict__ b1, const float* __restrict__ g1,
    const float* __restrict__ bb1, const float* __restrict__ w2,
    const float* __restrict__ b2, float* __restrict__ cis) {
  __shared__ float gm[256];
  __shared__ float c1[32];
  const int b = blockIdx.x, tid = threadIdx.x;
  for (int c = tid; c < 256; c += 128) {
    float s = 0.f;
    for (int p = 0; p < 128; ++p) s += gp[(size_t)(b * 128 + p) * 256 + c];
    gm[c] = s * (1.f / 4096.f);
  }
  __syncthreads();
  if (tid < 32) {
    float s = b1[tid];
    for (int c = 0; c < 256; ++c) s = fmaf(gm[c], w1[tid * 256 + c], s);
    s = s * (g1[tid] * BNR) + bb1[tid];
    c1[tid] = gelu_f(s);
  }
  __syncthreads();
  float s = b2[tid];
#pragma unroll
  for (int i = 0; i < 32; ++i) s = fmaf(c1[i], w2[tid * 32 + i], s);
  cis[b * 128 + tid] = 1.f / (1.f + __expf(-s));
}

// ---------------------------------------------------------------- k4
// qkv GEMM (bf16 MFMA) -> Q/K/VT f16 LDS -> S^T = K·Q^T via mfma 16x16x16f16
// (swapped trick: P^T D-layout == PV A-layout), softmax in-register, PV MFMA.
__global__ __launch_bounds__(256) void k4_attn(
    const unsigned short* __restrict__ xa, const unsigned short* __restrict__ qwp,
    const float* __restrict__ qb, const float* __restrict__ cis,
    const float* __restrict__ rpb, unsigned short* __restrict__ attn) {
  __shared__ _Float16 Qs[64][130];
  __shared__ _Float16 Ks[64][130];
  __shared__ _Float16 VT[128][66];
  __shared__ float bsl[8][226];
  __shared__ float cisl[128];
  __shared__ float qbl[384];
  const int tid = threadIdx.x;
  const int win = blockIdx.x, img = win >> 6;
  for (int i = tid; i < 1800; i += 256) bsl[i & 7][i >> 3] = rpb[i];
  for (int i = tid; i < 128; i += 256) cisl[i] = cis[img * 128 + i];
  for (int i = tid; i < 384; i += 256) qbl[i] = qb[i];
  const int w = tid >> 6, l = tid & 63, lr = l & 15, lg4 = l >> 4;
  short8 a[4];
  const unsigned short* ap = xa + (size_t)(win * 64 + w * 16 + lr) * 128 + lg4 * 8;
#pragma unroll
  for (int ks = 0; ks < 4; ++ks) a[ks] = *(const short8*)(ap + ks * 32);
  f32x4 acc[24];
#pragma unroll
  for (int nt = 0; nt < 24; ++nt) acc[nt] = (f32x4)0.f;
#pragma unroll
  for (int nt = 0; nt < 24; ++nt)
#pragma unroll
    for (int ks = 0; ks < 4; ++ks) {
      const short8 bfr = *(const short8*)(qwp + ((ks * 24 + nt) * 64 + l) * 8);
      acc[nt] = __builtin_amdgcn_mfma_f32_16x16x32_bf16(a[ks], bfr, acc[nt], 0, 0, 0);
    }
  __syncthreads();  // cisl/qbl/bsl ready
#pragma unroll
  for (int nt = 0; nt < 24; ++nt) {
    const int col = nt * 16 + lr;
#pragma unroll
    for (int j = 0; j < 4; ++j) {
      const int row = w * 16 + lg4 * 4 + j;
      const float v = acc[nt][j] + qbl[col];
      if (nt < 8) Qs[row][col] = (_Float16)(v * 0.25f);
      else if (nt < 16) Ks[row][col - 128] = (_Float16)v;
      else VT[col - 256][row] = (_Float16)(v * cisl[col - 256]);
    }
  }
  __syncthreads();
  for (int hi = 0; hi < 2; ++hi) {
    const int h = w * 2 + hi;
    half4 aK[4], bQ[4], bV[4];
#pragma unroll
    for (int mt = 0; mt < 4; ++mt)
      aK[mt] = *(const half4*)&Ks[mt * 16 + lr][h * 16 + lg4 * 4];
#pragma unroll
    for (int nt = 0; nt < 4; ++nt)
      bQ[nt] = *(const half4*)&Qs[nt * 16 + lr][h * 16 + lg4 * 4];
#pragma unroll
    for (int kt = 0; kt < 4; ++kt)
      bV[kt] = *(const half4*)&VT[h * 16 + lr][kt * 16 + lg4 * 4];
    f32x4 s[4][4];
#pragma unroll
    for (int mt = 0; mt < 4; ++mt)
#pragma unroll
      for (int nt = 0; nt < 4; ++nt)
        s[mt][nt] = __builtin_amdgcn_mfma_f32_16x16x16f16(aK[mt], bQ[nt],
                                                          (f32x4)0.f, 0, 0, 0);
#pragma unroll
    for (int mt = 0; mt < 4; ++mt) {
      const int m0 = mt * 16 + lg4 * 4;
#pragma unroll
      for (int r = 0; r < 4; ++r) {
        const int m = m0 + r;
        const int my = m >> 3, mxx = m & 7;
#pragma unroll
        for (int nt = 0; nt < 4; ++nt) {
          const int n = nt * 16 + lr;
          s[mt][nt][r] += bsl[h][((n >> 3) - my + 7) * 15 + (n & 7) - mxx + 7];
        }
      }
    }
    float inv[4];
#pragma unroll
    for (int nt = 0; nt < 4; ++nt) {
      float m0 = -1e30f;
#pragma unroll
      for (int mt = 0; mt < 4; ++mt)
#pragma unroll
        for (int r = 0; r < 4; ++r) m0 = fmaxf(m0, s[mt][nt][r]);
      m0 = fmaxf(m0, __shfl_xor(m0, 16));
      m0 = fmaxf(m0, __shfl_xor(m0, 32));
      float d0 = 0.f;
#pragma unroll
      for (int mt = 0; mt < 4; ++mt)
#pragma unroll
        for (int r = 0; r < 4; ++r) {
          const float e = __expf(s[mt][nt][r] - m0);
          s[mt][nt][r] = e;
          d0 += e;
        }
      d0 += __shfl_xor(d0, 16);
      d0 += __shfl_xor(d0, 32);
      inv[nt] = 1.f / d0;
    }
    half4 pa[4][4];
#pragma unroll
    for (int nt = 0; nt < 4; ++nt)
#pragma unroll
      for (int kt = 0; kt < 4; ++kt) {
        half4 p;
#pragma unroll
        for (int r = 0; r < 4; ++r) p[r] = (_Float16)(s[kt][nt][r] * inv[nt]);
        pa[nt][kt] = p;
      }
    f32x4 o[4];
#pragma unroll
    for (int nt = 0; nt < 4; ++nt) o[nt] = (f32x4)0.f;
#pragma unroll
    for (int nt = 0; nt < 4; ++nt)
#pragma unroll
      for (int kt = 0; kt < 4; ++kt)
        o[nt] = __builtin_amdgcn_mfma_f32_16x16x16f16(pa[nt][kt], bV[kt], o[nt], 0, 0, 0);
#pragma unroll
    for (int nt = 0; nt < 4; ++nt)
#pragma unroll
      for (int r = 0; r < 4; ++r) {
        const int token = win * 64 + nt * 16 + lg4 * 4 + r;
        attn[(size_t)token * 128 + h * 16 + lr] = f2bf(o[nt][r]);
      }
  }
}

// ---------------------------------------------------------------- k6
// Swizzled At tile; LN stats; si-MLP via MFMA; gating; final GEMM via MFMA.
__global__ __launch_bounds__(256) void k6_tail(
    const unsigned short* __restrict__ attn, const unsigned short* __restrict__ xpr,
    const unsigned short* __restrict__ sw1p, const float* __restrict__ sb1,
    const float* __restrict__ sgc, const float* __restrict__ sbc,
    const float* __restrict__ sw2, const float* __restrict__ sb2,
    const float* __restrict__ cg, const float* __restrict__ cbb,
    const float* __restrict__ ag, const float* __restrict__ abb,
    const unsigned short* __restrict__ owp, const float* __restrict__ ob,
    float* __restrict__ out) {
  __shared__ unsigned short At[64 * 256];
  __shared__ float sifl[64];
  __shared__ float statl[64][2];
  const int tid = threadIdx.x;
  const int R0 = blockIdx.x * 64;
  const int w = tid >> 6, l = tid & 63, lr = l & 15, lg4 = l >> 4;
  for (int i = tid; i < 1024; i += 256) {
    const int r = i >> 4, c16 = i & 15;
    *(uint4*)&At[ATI(r, c16)] =
        *(const uint4*)&attn[(size_t)(R0 + r) * 128 + c16 * 8];
    const int R = R0 + r, win = R >> 6, tt = R & 63;
    const int bimg = win >> 6, wy = (win >> 3) & 7, wx = win & 7;
    const int pix = (bimg * 64 + wy * 8 + (tt >> 3)) * 64 + wx * 8 + (tt & 7);
    *(uint4*)&At[ATI(r, 16 + c16)] =
        *(const uint4*)&xpr[(size_t)pix * 128 + c16 * 8];
  }
  __syncthreads();
  // LN stats over attn half
  {
    const int r = tid >> 2, q = tid & 3;
    float xv[32];
#pragma unroll
    for (int b8 = 0; b8 < 4; ++b8) ld8(&At[ATI(r, q * 4 + b8)], xv + b8 * 8);
    float ps = 0.f, pq = 0.f;
#pragma unroll
    for (int j = 0; j < 32; ++j) { ps += xv[j]; pq += xv[j] * xv[j]; }
    ps += __shfl_xor(ps, 1); ps += __shfl_xor(ps, 2);
    pq += __shfl_xor(pq, 1); pq += __shfl_xor(pq, 2);
    if (q == 0) {
      const float mean = ps * (1.f / 128.f);
      const float var = pq * (1.f / 128.f) - mean * mean;
      statl[r][0] = mean;
      statl[r][1] = rsqrtf(var + 1e-5f);
    }
  }
  // si MLP via MFMA on raw attn half: (16 rows x 128) @ (128 x 16)
  {
    const int row = w * 16 + lr;
    f32x4 sa = (f32x4)0.f;
#pragma unroll
    for (int ks = 0; ks < 4; ++ks) {
      const short8 a4 = *(const short8*)&At[ATI(row, ks * 4 + lg4)];
      const short8 bfr = *(const short8*)(sw1p + (ks * 64 + l) * 8);
      sa = __builtin_amdgcn_mfma_f32_16x16x32_bf16(a4, bfr, sa, 0, 0, 0);
    }
    const float sb1v = sb1[lr], g1v = sgc[lr] * BNR, b1v = sbc[lr];
    const float w2v = sw2[lr], sb2v = sb2[0];
#pragma unroll
    for (int j = 0; j < 4; ++j) {
      float s = (sa[j] + sb1v) * g1v + b1v;
      float p = gelu_f(s) * w2v;
      p += __shfl_xor(p, 1); p += __shfl_xor(p, 2);
      p += __shfl_xor(p, 4); p += __shfl_xor(p, 8);
      if (lr == 0) sifl[w * 16 + lg4 * 4 + j] = p + sb2v;
    }
  }
  __syncthreads();
  // gating + LN apply (per-thread fixed column c)
  {
    const int c = tid & 127;
    const float agv = ag[c], abbv = abb[c];
    const float cgv = cg[c] * BNR, cbbv = cbb[c];
#pragma unroll
    for (int k = 0; k < 32; ++k) {
      const int r = (tid >> 7) + k * 2;
      const int ia = ATI(r, c >> 3) + (c & 7);
      const int ic = ATI(r, 16 + (c >> 3)) + (c & 7);
      float a = bf2f(At[ia]);
      a = (a - statl[r][0]) * statl[r][1] * agv + abbv;
      At[ia] = f2bf(a);
      const float cv = bf2f(At[ic]);
      const float g = 1.f / (1.f + __expf(-sifl[r] * cv));
      At[ic] = f2bf(g * cgv + cbbv);
    }
  }
  __syncthreads();
  // final GEMM (64 x 256) @ (256 x 256)
  const int row = w * 16 + lr;
  short8 a[8];
#pragma unroll
  for (int ks = 0; ks < 8; ++ks)
    a[ks] = *(const short8*)&At[ATI(row, ks * 4 + lg4)];
  f32x4 acc[16];
#pragma unroll
  for (int nt = 0; nt < 16; ++nt) acc[nt] = (f32x4)0.f;
#pragma unroll
  for (int nt = 0; nt < 16; ++nt)
#pragma unroll
    for (int ks = 0; ks < 8; ++ks) {
      const short8 bfr = *(const short8*)(owp + ((ks * 16 + nt) * 64 + l) * 8);
      acc[nt] = __builtin_amdgcn_mfma_f32_16x16x32_bf16(a[ks], bfr, acc[nt], 0, 0, 0);
    }
#pragma unroll
  for (int nt = 0; nt < 16; ++nt) {
    const int col = nt * 16 + lr;
    const float bv = ob[col];
#pragma unroll
    for (int j = 0; j < 4; ++j)
      out[(size_t)(R0 + w * 16 + lg4 * 4 + j) * 256 + col] = acc[nt][j] + bv;
  }
}

// ---------------------------------------------------------------- launch
extern "C" void kernel_launch(void* const* d_in, const int* in_sizes, int n_in,
                              void* d_out, int out_size, void* d_ws,
                              size_t ws_size, hipStream_t stream) {
  (void)in_sizes; (void)n_in; (void)out_size; (void)ws_size;
  const float* x      = (const float*)d_in[0];
  const float* rpb    = (const float*)d_in[1];
  const float* attn_w = (const float*)d_in[2];
  const float* attn_b = (const float*)d_in[3];
  const float* aln_g  = (const float*)d_in[4];
  const float* aln_b  = (const float*)d_in[5];
  const float* conv_w = (const float*)d_in[6];
  const float* conv_b = (const float*)d_in[7];
  const float* cbn_g  = (const float*)d_in[8];
  const float* cbn_b  = (const float*)d_in[9];
  const float* ci_w1  = (const float*)d_in[10];
  const float* ci_b1  = (const float*)d_in[11];
  const float* ci_bg  = (const float*)d_in[12];
  const float* ci_bb  = (const float*)d_in[13];
  const float* ci_w2  = (const float*)d_in[14];
  const float* ci_b2  = (const float*)d_in[15];
  const float* pr_w   = (const float*)d_in[16];
  const float* pr_b   = (const float*)d_in[17];
  const float* cn_g   = (const float*)d_in[18];
  const float* cn_b   = (const float*)d_in[19];
  const float* qkv_w  = (const float*)d_in[20];
  const float* qkv_b  = (const float*)d_in[21];
  const float* si_w1  = (const float*)d_in[22];
  const float* si_b1  = (const float*)d_in[23];
  const float* si_bg  = (const float*)d_in[24];
  const float* si_bb  = (const float*)d_in[25];
  const float* si_w2  = (const float*)d_in[26];
  const float* si_b2  = (const float*)d_in[27];
  const float* an_g   = (const float*)d_in[28];
  const float* an_b   = (const float*)d_in[29];
  const float* out_w  = (const float*)d_in[30];
  const float* out_b  = (const float*)d_in[31];

  unsigned short* xb    = (unsigned short*)d_ws;          // 33,554,432 e
  unsigned short* xattn = xb + 33554432;                  // 16,777,216 e
  unsigned short* attn  = xattn + 16777216;               // 16,777,216 e
  unsigned short* xpr   = attn + 16777216;                // 16,777,216 e
  float* gpart = (float*)(xpr + 16777216);                // 1,048,576 f
  float* cis   = gpart + 1048576;                         // 4,096 f
  unsigned short* awp  = (unsigned short*)(cis + 4096);   // 32,768 e
  unsigned short* qwp  = awp + 32768;                     // 49,152 e
  unsigned short* prwp = qwp + 49152;                     // 32,768 e
  unsigned short* owp  = prwp + 32768;                    // 65,536 e
  unsigned short* sw1p = owp + 65536;                     // 2,048 e

  kpack<<<356, 256, 0, stream>>>(attn_w, qkv_w, pr_w, out_w, si_w1,
                                 awp, qwp, prwp, owp, sw1p);
  k1_attn_ln<<<2048, 256, 0, stream>>>(x, awp, attn_b, aln_g, aln_b, xattn, xb);
  k25_conv<<<4096, 256, 0, stream>>>(xb, conv_w, conv_b, cbn_g, cbn_b, prwp,
                                     pr_b, xpr, gpart);
  k3_ci<<<32, 128, 0, stream>>>(gpart, ci_w1, ci_b1, ci_bg, ci_bb, ci_w2,
                                ci_b2, cis);
  k4_attn<<<2048, 256, 0, stream>>>(xattn, qwp, qkv_b, cis, rpb, attn);
  k6_tail<<<2048, 256, 0, stream>>>(attn, xpr, sw1p, si_b1, si_bg, si_bb,
                                    si_w2, si_b2, cn_g, cn_b, an_g, an_b,
                                    owp, out_b, (float*)d_out);
}